// Round 15
// baseline (361.166 us; speedup 1.0000x reference)
//
#include <hip/hip_runtime.h>
#include <hip/hip_bf16.h>
#include <math.h>

// GNNLayer: B=4,T=4096,D=128,H=4,DH=32,FF=256
// bf16 MFMA (16x16x32) everywhere, fp32 accum, fp32 LN/residual/bias.
// R15: rest-sweep with attribution discipline:
//      - k_detect: 1 block -> 64 blocks (wave-__all + <=2 atomics/wave);
//        flags/kmax2 init via hipMemsetAsync (capture-legal).
//      - k_pack u8 path: 2 x uint4 + nibble-collapse mul trick (no arrays).
//      - k_qkv: fuses conv_x (x f32 -> LDS bf16 tile) and knorm (from staged
//        LDS epilogue tile, atomicMax). 8 kernels -> 6.
//      - attn/tail byte-identical to R14 (92.7us / proven).

#define B_ 4
#define T_ 4096
#define D_ 128
#define H_ 4
#define DH_ 32
#define FF_ 256
#define M_ (B_*T_)

typedef unsigned short u16;
typedef __attribute__((ext_vector_type(8))) short bf16x8;
typedef __attribute__((ext_vector_type(4))) float f32x4;
typedef __attribute__((ext_vector_type(4))) u16 u16x4;

// ---- workspace layout (bytes, 256-aligned) ----
constexpr size_t OFF_FLAG  = 0;     // u32 flags[2] @0 (i32-ok, f32-ok), float kmax2[16] @64
constexpr size_t OFF_MASKW = 256;                      // u32[T][T/32] = 2 MB
constexpr size_t OFF_XB    = OFF_MASKW + 2097152;      // (unused after R15 fusion)
constexpr size_t OFF_WQKVT = OFF_XB    + 4194304;      // bf16 [384][128]
constexpr size_t OFF_WOT   = OFF_WQKVT + 98304;        // bf16 [128][128]
constexpr size_t OFF_W1T   = OFF_WOT   + 32768;        // bf16 [256][128]
constexpr size_t OFF_W2T   = OFF_W1T   + 65536;        // bf16 [128][256]
constexpr size_t OFF_QW    = OFF_W2T   + 65536;        // bf16 [16][T][32] (q, pre-scaled 1/sqrt(DH))
constexpr size_t OFF_KW    = OFF_QW    + 4194304;      // bf16 [16][T*32] fragment-major
constexpr size_t OFF_VT    = OFF_KW    + 4194304;      // bf16 [16][T*32] fragment-major v^T
constexpr size_t OFF_AO    = OFF_VT    + 4194304;      // bf16 attn out [M][128]

__device__ __forceinline__ u16 f2bf(float f){
  unsigned u = __float_as_uint(f);
  u += 0x7FFFu + ((u >> 16) & 1u);
  return (u16)(u >> 16);
}

__device__ __forceinline__ float bf2f(u16 b){
  return __uint_as_float((unsigned)b << 16);
}

// frag loader (row-major source, works for global or LDS):
// p = base + row*stride + k0 + 4*(lane>>4)
__device__ __forceinline__ bf16x8 load_frag(const u16* p){
  union { bf16x8 v; uint2 u[2]; } f;
  f.u[0] = *(const uint2*)(p);
  f.u[1] = *(const uint2*)(p + 16);
  return f.v;
}

// ---- mask dtype detection: 64 blocks over first 16384 words ----
// flags pre-set to nonzero by memset; atomicAnd(0) falsifies.
__global__ void k_detect(const unsigned* m, unsigned* flags){
  const int i = blockIdx.x*256 + threadIdx.x;
  const unsigned w = m[i];
  const int li = (w <= 1u);
  const int lf = (w == 0u || w == 0x3F800000u);
  if (!__all(li)){ if ((threadIdx.x & 63) == 0) atomicAnd(&flags[0], 0u); }
  if (!__all(lf)){ if ((threadIdx.x & 63) == 0) atomicAnd(&flags[1], 0u); }
}

// pack (adj | eye) into bits: mw[i*128 + j/32] bit (j%32).
__global__ void k_pack(const void* mask, const unsigned* flags, unsigned* mw){
  int idx = blockIdx.x*256 + threadIdx.x;   // word index, T*T/32 total
  int i = idx >> 7, wj = idx & 127;
  unsigned w = 0;
  if (flags[0] | flags[1]){
    // 4-byte elements
    const uint4* p = (const uint4*)((const unsigned*)mask + (size_t)i*T_ + wj*32);
    #pragma unroll
    for (int j = 0; j < 8; j++){
      uint4 v = p[j];
      w |= (unsigned)(v.x != 0u) << (4*j);
      w |= (unsigned)(v.y != 0u) << (4*j + 1);
      w |= (unsigned)(v.z != 0u) << (4*j + 2);
      w |= (unsigned)(v.w != 0u) << (4*j + 3);
    }
  } else {
    // 1-byte bool elements: collapse 4 bytes -> 4 bits via carry-free mul
    // ((d & 0x01010101) * 0x01020408) >> 24 puts b0..b3 at bits 0..3.
    const uint4* p = (const uint4*)((const unsigned char*)mask + (size_t)i*T_ + wj*32);
    uint4 A = p[0], B = p[1];
    #define NIB_(d) ((((d) & 0x01010101u) * 0x01020408u) >> 24)
    w  =  NIB_(A.x)        | (NIB_(A.y) << 4)  | (NIB_(A.z) << 8)  | (NIB_(A.w) << 12)
       | (NIB_(B.x) << 16) | (NIB_(B.y) << 20) | (NIB_(B.z) << 24) | (NIB_(B.w) << 28);
    #undef NIB_
  }
  if ((i >> 5) == wj) w |= 1u << (i & 31);
  mw[idx] = w;
}

// weights -> bf16, transposed [N][K]
__global__ void k_conv_w(const float* Wq, const float* Wk, const float* Wv, const float* Wo,
                         const float* W1, const float* W2,
                         u16* wqkvt, u16* wot, u16* w1t, u16* w2t){
  int idx = blockIdx.x*256 + threadIdx.x;
  if (idx < 49152){                      // wqkvt[n<384][k<128]
    int n = idx >> 7, k = idx & 127;
    float v = (n < 128) ? Wq[k*128 + n] : (n < 256 ? Wk[k*128 + (n-128)] : Wv[k*128 + (n-256)]);
    wqkvt[idx] = f2bf(v);
  } else if (idx < 65536){               // wot[n<128][k<128]
    int j = idx - 49152, n = j >> 7, k = j & 127;
    wot[j] = f2bf(Wo[k*128 + n]);
  } else if (idx < 98304){               // w1t[n<256][k<128]
    int j = idx - 65536, n = j >> 7, k = j & 127;
    w1t[j] = f2bf(W1[k*256 + n]);
  } else if (idx < 131072){              // w2t[n<128][k<256]
    int j = idx - 98304, n = j >> 8, k = j & 255;
    w2t[j] = f2bf(W2[k*128 + n]);
  }
}

// QKV GEMM (fused conv_x + knorm): grid 1024 (16 rows each), 4 waves x 96 cols.
// x read as f32 -> LDS bf16 tile; epilogue LDS-staged, vectorized emit;
// per-key ||k||^2 computed from the staged tile -> atomicMax kmax2.
__global__ __launch_bounds__(256) void k_qkv(const float* x, const u16* wt,
    const float* bq, const float* bk, const float* bv,
    u16* qw, u16* kw, u16* vt, float* kmax2){
  __shared__ u16 xt[16][136];   // x tile bf16, padded
  __shared__ u16 st[16][392];   // [row][ncol 0..383] epilogue stage, padded
  const int wv = threadIdx.x >> 6, lane = threadIdx.x & 63;
  const int r15 = lane & 15, g = lane >> 4;
  const int m0 = blockIdx.x * 16;
  // load + convert x tile (thread -> row i>>4, cols (i&15)*8 .. +7)
  {
    const int row = threadIdx.x >> 4, c0 = (threadIdx.x & 15) * 8;
    const float* xp = x + (size_t)(m0 + row)*D_ + c0;
    float4 a = *(const float4*)(xp);
    float4 b = *(const float4*)(xp + 4);
    u16x4 o1 = { f2bf(a.x), f2bf(a.y), f2bf(a.z), f2bf(a.w) };
    u16x4 o2 = { f2bf(b.x), f2bf(b.y), f2bf(b.z), f2bf(b.w) };
    *(u16x4*)&xt[row][c0]     = o1;
    *(u16x4*)&xt[row][c0 + 4] = o2;
  }
  __syncthreads();
  f32x4 acc[6] = {};
  #pragma unroll
  for (int kk = 0; kk < D_; kk += 32){
    bf16x8 af = load_frag(&xt[r15][kk + 4*g]);
    #pragma unroll
    for (int nf = 0; nf < 6; nf++){
      const u16* br = wt + (size_t)(wv*96 + nf*16 + r15)*D_ + kk + 4*g;
      acc[nf] = __builtin_amdgcn_mfma_f32_16x16x32_bf16(af, load_frag(br), acc[nf], 0, 0, 0);
    }
  }
  // stage to LDS with bias (+ q scale)
  #pragma unroll
  for (int nf = 0; nf < 6; nf++){
    int ncol = wv*96 + nf*16 + r15;
    float bias = (ncol < 128) ? bq[ncol] : (ncol < 256 ? bk[ncol-128] : bv[ncol-256]);
    float scl  = (ncol < 128) ? 0.17677669529663687f : 1.f;   // 1/sqrt(32) on q
    #pragma unroll
    for (int rr = 0; rr < 4; rr++)
      st[4*g + rr][ncol] = f2bf((acc[nf][rr] + bias) * scl);
  }
  __syncthreads();
  // vectorized emit
  const int b = m0 >> 12, t0m = m0 & (T_-1);
  const int i = threadIdx.x;
  // Q: 256 x 16B. i -> t=i>>4, c=i&15 (h=c>>2, d0=(c&3)*8)
  {
    const int t = i >> 4, c = i & 15, h = c >> 2, d0 = (c & 3)*8;
    uint4 v = *(const uint4*)&st[t][h*32 + d0];
    *(uint4*)(qw + ((size_t)(b*H_ + h)*T_ + (t0m + t))*DH_ + d0) = v;
  }
  // K: 256 x 16B. i -> h=i>>6, seg=(i>>4)&3, trow=i&15.
  {
    const int h = i >> 6, seg = (i >> 4) & 3, trow = i & 15;
    union { u16 e[8]; uint4 u; } v;
    #pragma unroll
    for (int sub = 0; sub < 8; sub++){
      int d = 16*(sub >> 2) + 4*seg + (sub & 3);
      v.e[sub] = st[trow][128 + h*32 + d];
    }
    *(uint4*)(kw + (size_t)(b*H_ + h)*T_*DH_ + (size_t)(t0m >> 4)*512 + seg*128 + trow*8) = v.u;
  }
  // V: 512 x 8B (2 chunks/thread).
  {
    const int bit4 = (t0m >> 4) & 1;
    #pragma unroll
    for (int cc = 0; cc < 2; cc++){
      const int c = i + cc*256;
      const int h = c >> 7, dlhi = (c >> 6) & 1, tq = (c >> 4) & 3, dl15 = c & 15;
      u16x4 v;
      #pragma unroll
      for (int j = 0; j < 4; j++)
        v[j] = st[tq*4 + j][256 + h*32 + dlhi*16 + dl15];
      *(u16x4*)(vt + (size_t)(b*H_ + h)*T_*DH_ + (size_t)(t0m >> 5)*1024
                + dlhi*512 + (size_t)(tq*16 + dl15)*8 + 4*bit4) = v;
    }
  }
  // knorm: per-key ||k||^2 from staged tile (threads 0..63: t=i>>2, h=i&3)
  if (i < 64){
    const int t = i >> 2, h = i & 3;
    float s = 0.f;
    #pragma unroll
    for (int d = 0; d < 32; d++){ float f = bf2f(st[t][128 + h*32 + d]); s += f*f; }
    atomicMax((unsigned*)(kmax2 + (b*H_ + h)), __float_as_uint(s));
  }
}

// Bounded-softmax attention (__expf). Swapped QK^T; shift+mask in C-init;
// l via ones-column MFMA; pack via __float22bfloat162_rn. (exact R10 kernel)
// grid = BH(16) * T/64 = 1024; 4 waves/block, 16 queries/wave. XCD swizzle.
__global__ __launch_bounds__(256, 4) void k_attn15(const u16* qw, const u16* kw, const u16* vt,
    const unsigned* mw, const float* kmax2, u16* ao){
  const int wg = (blockIdx.x & 7)*128 + (blockIdx.x >> 3);   // 8 XCDs x 128 contiguous
  const int wv = threadIdx.x >> 6, lane = threadIdx.x & 63;
  const int r15 = lane & 15, g = lane >> 4;
  const int bh = wg >> 6;
  const int q0 = (wg & 63)*64 + wv*16;
  const u16* qp = qw + (size_t)bh*T_*DH_;
  const u16* kl = kw + (size_t)bh*T_*DH_ + lane*8;   // fragment-major, lane offset folded
  const u16* vl = vt + (size_t)bh*T_*DH_ + lane*8;
  const unsigned* mrow = mw + (size_t)(q0 + r15)*(T_/32);
  const bf16x8 qf = load_frag(qp + (size_t)(q0 + r15)*DH_ + 4*g);
  float n0 = 0.f;
  #pragma unroll
  for (int j = 0; j < 8; j++){ float f = bf2f((u16)qf[j]); n0 += f*f; }
  n0 += __shfl_xor(n0, 16); n0 += __shfl_xor(n0, 32);
  const float bnd = sqrtf(n0 * kmax2[bh]) * 1.0001f + 1e-6f;  // >= max_j |q.k_j|
  union { u16 e[8]; bf16x8 v; } ones;
  #pragma unroll
  for (int j = 0; j < 8; j++) ones.e[j] = 0x3F80;
  f32x4 o0 = {}, o1 = {}, ol = {};
  for (int jb4 = 0; jb4 < T_; jb4 += 128){
    const uint4 wv4 = *(const uint4*)(mrow + (jb4 >> 5));
    #pragma unroll
    for (int ji = 0; ji < 4; ji++){
      const int jb = jb4 + ji*32;
      const unsigned w = ((const unsigned*)&wv4)[ji];
      const unsigned u = w >> (4*g);
      bf16x8 kf0 = *(const bf16x8*)(kl + (size_t)(jb >> 4)*512);
      bf16x8 kf1 = *(const bf16x8*)(kl + (size_t)((jb >> 4) + 1)*512);
      bf16x8 vf0 = *(const bf16x8*)(vl + (size_t)(jb >> 5)*1024);
      bf16x8 vf1 = *(const bf16x8*)(vl + (size_t)(jb >> 5)*1024 + 512);
      f32x4 c0, c1;   // -bnd if masked-in else -1e30 (exp -> 0)
      #pragma unroll
      for (int rr = 0; rr < 4; rr++){
        c0[rr] = ((u >> rr) & 1u)        ? -bnd : -1e30f;
        c1[rr] = ((u >> (16 + rr)) & 1u) ? -bnd : -1e30f;
      }
      f32x4 s0 = __builtin_amdgcn_mfma_f32_16x16x32_bf16(kf0, qf, c0, 0, 0, 0);
      f32x4 s1 = __builtin_amdgcn_mfma_f32_16x16x32_bf16(kf1, qf, c1, 0, 0, 0);
      float p0[4], p1[4];
      #pragma unroll
      for (int rr = 0; rr < 4; rr++){
        p0[rr] = __expf(s0[rr]);
        p1[rr] = __expf(s1[rr]);
      }
      union { bf16x8 v; __hip_bfloat162 h2[4]; } pf;
      pf.h2[0] = __float22bfloat162_rn(make_float2(p0[0], p0[1]));
      pf.h2[1] = __float22bfloat162_rn(make_float2(p0[2], p0[3]));
      pf.h2[2] = __float22bfloat162_rn(make_float2(p1[0], p1[1]));
      pf.h2[3] = __float22bfloat162_rn(make_float2(p1[2], p1[3]));
      o0 = __builtin_amdgcn_mfma_f32_16x16x32_bf16(pf.v, vf0, o0, 0, 0, 0);
      o1 = __builtin_amdgcn_mfma_f32_16x16x32_bf16(pf.v, vf1, o1, 0, 0, 0);
      ol = __builtin_amdgcn_mfma_f32_16x16x32_bf16(pf.v, ones.v, ol, 0, 0, 0);
    }
  }
  const int b = bh >> 2, h = bh & 3;
  #pragma unroll
  for (int rr = 0; rr < 4; rr++){
    float li = ol[rr];                  // l for query 4g+rr, present in every lane
    float inv = li > 0.f ? 1.f/li : 0.f;
    size_t row = (size_t)(b*T_ + q0 + 4*g + rr)*D_;
    ao[row + h*DH_ + r15]      = f2bf(o0[rr]*inv);
    ao[row + h*DH_ + 16 + r15] = f2bf(o1[rr]*inv);
  }
}

// Fused tail: proj+residual+LN1 -> FF1+GELU -> FF2+residual+LN2 -> out.
// grid 1024 (16 rows/block), 4 waves. y/h staged in LDS (padded rows).
__global__ __launch_bounds__(256) void k_tail(const u16* ao, const u16* wot, const float* bo,
    const float* x, const float* g1, const float* be1,
    const u16* w1t, const float* bf1, const u16* w2t, const float* b2,
    const float* g2, const float* be2, float* out){
  __shared__ float ly[16][132];     // y32 (LN1 out, f32) - LN2 residual
  __shared__ u16  lyb[16][136];     // y bf16 (A for FF1)
  __shared__ u16  lhb[16][264];     // gelu(h) bf16 (A for FF2)
  __shared__ float rs[4][16], rq[4][16];
  const int wv = threadIdx.x >> 6, lane = threadIdx.x & 63;
  const int r15 = lane & 15, g = lane >> 4;
  const int m0 = blockIdx.x * 16;

  // ---- stage A: proj GEMM (wave wv -> cols [wv*32, wv*32+32)) ----
  f32x4 accA[2] = {};
  const u16* ar = ao + (size_t)(m0 + r15)*D_ + 4*g;
  #pragma unroll
  for (int kk = 0; kk < D_; kk += 32){
    bf16x8 af = load_frag(ar + kk);
    #pragma unroll
    for (int nf = 0; nf < 2; nf++)
      accA[nf] = __builtin_amdgcn_mfma_f32_16x16x32_bf16(af,
          load_frag(wot + (size_t)((wv*2 + nf)*16 + r15)*D_ + kk + 4*g), accA[nf], 0, 0, 0);
  }
  float tA[2][4];
  #pragma unroll
  for (int rr = 0; rr < 4; rr++){
    float s1 = 0.f, s2 = 0.f;
    #pragma unroll
    for (int nf = 0; nf < 2; nf++){
      int col = (wv*2 + nf)*16 + r15;
      float t = accA[nf][rr] + bo[col] + x[(size_t)(m0 + 4*g + rr)*D_ + col];
      tA[nf][rr] = t; s1 += t; s2 += t*t;
    }
    #pragma unroll
    for (int d = 1; d < 16; d <<= 1){ s1 += __shfl_xor(s1, d); s2 += __shfl_xor(s2, d); }
    if (r15 == 0){ rs[wv][4*g + rr] = s1; rq[wv][4*g + rr] = s2; }
  }
  __syncthreads();
  #pragma unroll
  for (int rr = 0; rr < 4; rr++){
    int row = 4*g + rr;
    float S1 = rs[0][row] + rs[1][row] + rs[2][row] + rs[3][row];
    float S2 = rq[0][row] + rq[1][row] + rq[2][row] + rq[3][row];
    float mu = S1 * (1.f/D_);
    float var = fmaxf(S2 * (1.f/D_) - mu*mu, 0.f);
    float inv = rsqrtf(var + 1e-5f);
    #pragma unroll
    for (int nf = 0; nf < 2; nf++){
      int col = (wv*2 + nf)*16 + r15;
      float o = (tA[nf][rr] - mu)*inv*g1[col] + be1[col];
      ly[row][col] = o;
      lyb[row][col] = f2bf(o);
    }
  }
  __syncthreads();

  // ---- stage B: FF1 + GELU (wave wv -> cols [wv*64, wv*64+64)) ----
  const int n0w = wv*64;
  f32x4 accB[4] = {};
  #pragma unroll
  for (int kk = 0; kk < D_; kk += 32){
    bf16x8 af = load_frag(&lyb[r15][kk + 4*g]);
    #pragma unroll
    for (int nf = 0; nf < 4; nf++)
      accB[nf] = __builtin_amdgcn_mfma_f32_16x16x32_bf16(af,
          load_frag(w1t + (size_t)(n0w + nf*16 + r15)*D_ + kk + 4*g), accB[nf], 0, 0, 0);
  }
  #pragma unroll
  for (int nf = 0; nf < 4; nf++){
    int col = n0w + nf*16 + r15;
    float bias = bf1[col];
    #pragma unroll
    for (int rr = 0; rr < 4; rr++){
      float vv = accB[nf][rr] + bias;
      float z2 = fminf(1.5957691216057308f*vv + 0.07135581778225507f*vv*vv*vv, 80.f);
      float t = __expf(z2);
      lhb[4*g + rr][col] = f2bf(vv * t / (t + 1.f));
    }
  }
  __syncthreads();

  // ---- stage C: FF2 + residual + LN2 (wave wv -> cols [wv*32, wv*32+32)) ----
  f32x4 accC[2] = {};
  #pragma unroll
  for (int kk = 0; kk < FF_; kk += 32){
    bf16x8 af = load_frag(&lhb[r15][kk + 4*g]);
    #pragma unroll
    for (int nf = 0; nf < 2; nf++)
      accC[nf] = __builtin_amdgcn_mfma_f32_16x16x32_bf16(af,
          load_frag(w2t + (size_t)((wv*2 + nf)*16 + r15)*FF_ + kk + 4*g), accC[nf], 0, 0, 0);
  }
  float tC[2][4];
  #pragma unroll
  for (int rr = 0; rr < 4; rr++){
    float s1 = 0.f, s2 = 0.f;
    #pragma unroll
    for (int nf = 0; nf < 2; nf++){
      int col = (wv*2 + nf)*16 + r15;
      float t = accC[nf][rr] + b2[col] + ly[4*g + rr][col];
      tC[nf][rr] = t; s1 += t; s2 += t*t;
    }
    #pragma unroll
    for (int d = 1; d < 16; d <<= 1){ s1 += __shfl_xor(s1, d); s2 += __shfl_xor(s2, d); }
    if (r15 == 0){ rs[wv][4*g + rr] = s1; rq[wv][4*g + rr] = s2; }
  }
  __syncthreads();
  #pragma unroll
  for (int rr = 0; rr < 4; rr++){
    int row = 4*g + rr;
    float S1 = rs[0][row] + rs[1][row] + rs[2][row] + rs[3][row];
    float S2 = rq[0][row] + rq[1][row] + rq[2][row] + rq[3][row];
    float mu = S1 * (1.f/D_);
    float var = fmaxf(S2 * (1.f/D_) - mu*mu, 0.f);
    float inv = rsqrtf(var + 1e-5f);
    #pragma unroll
    for (int nf = 0; nf < 2; nf++){
      int col = (wv*2 + nf)*16 + r15;
      out[(size_t)(m0 + row)*D_ + col] = (tC[nf][rr] - mu)*inv*g2[col] + be2[col];
    }
  }
}

extern "C" void kernel_launch(void* const* d_in, const int* in_sizes, int n_in,
                              void* d_out, int out_size, void* d_ws, size_t ws_size,
                              hipStream_t stream){
  const float* x   = (const float*)d_in[0];
  const void*  msk = d_in[1];
  const float* Wq = (const float*)d_in[2];  const float* bq  = (const float*)d_in[3];
  const float* Wk = (const float*)d_in[4];  const float* bk  = (const float*)d_in[5];
  const float* Wv = (const float*)d_in[6];  const float* bv  = (const float*)d_in[7];
  const float* Wo = (const float*)d_in[8];  const float* bo  = (const float*)d_in[9];
  const float* g1 = (const float*)d_in[10]; const float* be1 = (const float*)d_in[11];
  const float* W1 = (const float*)d_in[12]; const float* bf1 = (const float*)d_in[13];
  const float* W2 = (const float*)d_in[14]; const float* b2  = (const float*)d_in[15];
  const float* g2 = (const float*)d_in[16]; const float* be2 = (const float*)d_in[17];

  char* ws = (char*)d_ws;
  unsigned* flags = (unsigned*)(ws + OFF_FLAG);
  float*    kmax2 = (float*)   (ws + OFF_FLAG + 64);
  unsigned* mw    = (unsigned*)(ws + OFF_MASKW);
  u16* wqkvt = (u16*)(ws + OFF_WQKVT);
  u16* wot   = (u16*)(ws + OFF_WOT);
  u16* w1t   = (u16*)(ws + OFF_W1T);
  u16* w2t   = (u16*)(ws + OFF_W2T);
  u16* qw    = (u16*)(ws + OFF_QW);
  u16* kw    = (u16*)(ws + OFF_KW);
  u16* vt    = (u16*)(ws + OFF_VT);
  u16* ao    = (u16*)(ws + OFF_AO);

  hipMemsetAsync(ws + OFF_FLAG, 1, 8, stream);        // flags = 0x01010101 (true)
  hipMemsetAsync(ws + OFF_FLAG + 64, 0, 64, stream);  // kmax2 = 0
  k_detect<<<64, 256, 0, stream>>>((const unsigned*)msk, flags);
  k_pack  <<<(T_*T_/32)/256, 256, 0, stream>>>(msk, flags, mw);
  k_conv_w<<<131072/256, 256, 0, stream>>>(Wq, Wk, Wv, Wo, W1, W2, wqkvt, wot, w1t, w2t);
  k_qkv   <<<M_/16, 256, 0, stream>>>(x, wqkvt, bq, bk, bv, qw, kw, vt, kmax2);
  k_attn15<<<(B_*H_)*(T_/64), 256, 0, stream>>>(qw, kw, vt, mw, kmax2, ao);
  k_tail  <<<M_/16, 256, 0, stream>>>(ao, wot, bo, x, g1, be1, w1t, bf1, w2t, b2, g2, be2, (float*)d_out);
}

// Round 16
// 187.961 us; speedup vs baseline: 1.9215x; 1.9215x over previous
//
#include <hip/hip_runtime.h>
#include <hip/hip_bf16.h>
#include <math.h>

// GNNLayer: B=4,T=4096,D=128,H=4,DH=32,FF=256
// bf16 MFMA (16x16x32) everywhere, fp32 accum, fp32 LN/residual/bias.
// R16: R15 with ONE fix: k_qkv's fused knorm tail issued 64 atomicMax/block
//      to 16 hot addresses (65536 serialized atomics -> 205us, VALUBusy 1%).
//      Now: 4-step shfl_xor max-reduce over t, then 4 atomics/block (lanes
//      0..3) = 4096 total (R13-proven scale). Everything else identical.

#define B_ 4
#define T_ 4096
#define D_ 128
#define H_ 4
#define DH_ 32
#define FF_ 256
#define M_ (B_*T_)

typedef unsigned short u16;
typedef __attribute__((ext_vector_type(8))) short bf16x8;
typedef __attribute__((ext_vector_type(4))) float f32x4;
typedef __attribute__((ext_vector_type(4))) u16 u16x4;

// ---- workspace layout (bytes, 256-aligned) ----
constexpr size_t OFF_FLAG  = 0;     // u32 flags[2] @0 (i32-ok, f32-ok), float kmax2[16] @64
constexpr size_t OFF_MASKW = 256;                      // u32[T][T/32] = 2 MB
constexpr size_t OFF_XB    = OFF_MASKW + 2097152;      // (unused after R15 fusion)
constexpr size_t OFF_WQKVT = OFF_XB    + 4194304;      // bf16 [384][128]
constexpr size_t OFF_WOT   = OFF_WQKVT + 98304;        // bf16 [128][128]
constexpr size_t OFF_W1T   = OFF_WOT   + 32768;        // bf16 [256][128]
constexpr size_t OFF_W2T   = OFF_W1T   + 65536;        // bf16 [128][256]
constexpr size_t OFF_QW    = OFF_W2T   + 65536;        // bf16 [16][T][32] (q, pre-scaled 1/sqrt(DH))
constexpr size_t OFF_KW    = OFF_QW    + 4194304;      // bf16 [16][T*32] fragment-major
constexpr size_t OFF_VT    = OFF_KW    + 4194304;      // bf16 [16][T*32] fragment-major v^T
constexpr size_t OFF_AO    = OFF_VT    + 4194304;      // bf16 attn out [M][128]

__device__ __forceinline__ u16 f2bf(float f){
  unsigned u = __float_as_uint(f);
  u += 0x7FFFu + ((u >> 16) & 1u);
  return (u16)(u >> 16);
}

__device__ __forceinline__ float bf2f(u16 b){
  return __uint_as_float((unsigned)b << 16);
}

// frag loader (row-major source, works for global or LDS):
// p = base + row*stride + k0 + 4*(lane>>4)
__device__ __forceinline__ bf16x8 load_frag(const u16* p){
  union { bf16x8 v; uint2 u[2]; } f;
  f.u[0] = *(const uint2*)(p);
  f.u[1] = *(const uint2*)(p + 16);
  return f.v;
}

// ---- mask dtype detection: 64 blocks over first 16384 words ----
// flags pre-set to nonzero by memset; atomicAnd(0) falsifies.
__global__ void k_detect(const unsigned* m, unsigned* flags){
  const int i = blockIdx.x*256 + threadIdx.x;
  const unsigned w = m[i];
  const int li = (w <= 1u);
  const int lf = (w == 0u || w == 0x3F800000u);
  if (!__all(li)){ if ((threadIdx.x & 63) == 0) atomicAnd(&flags[0], 0u); }
  if (!__all(lf)){ if ((threadIdx.x & 63) == 0) atomicAnd(&flags[1], 0u); }
}

// pack (adj | eye) into bits: mw[i*128 + j/32] bit (j%32).
__global__ void k_pack(const void* mask, const unsigned* flags, unsigned* mw){
  int idx = blockIdx.x*256 + threadIdx.x;   // word index, T*T/32 total
  int i = idx >> 7, wj = idx & 127;
  unsigned w = 0;
  if (flags[0] | flags[1]){
    // 4-byte elements
    const uint4* p = (const uint4*)((const unsigned*)mask + (size_t)i*T_ + wj*32);
    #pragma unroll
    for (int j = 0; j < 8; j++){
      uint4 v = p[j];
      w |= (unsigned)(v.x != 0u) << (4*j);
      w |= (unsigned)(v.y != 0u) << (4*j + 1);
      w |= (unsigned)(v.z != 0u) << (4*j + 2);
      w |= (unsigned)(v.w != 0u) << (4*j + 3);
    }
  } else {
    // 1-byte bool elements: collapse 4 bytes -> 4 bits via carry-free mul
    const uint4* p = (const uint4*)((const unsigned char*)mask + (size_t)i*T_ + wj*32);
    uint4 A = p[0], B = p[1];
    #define NIB_(d) ((((d) & 0x01010101u) * 0x01020408u) >> 24)
    w  =  NIB_(A.x)        | (NIB_(A.y) << 4)  | (NIB_(A.z) << 8)  | (NIB_(A.w) << 12)
       | (NIB_(B.x) << 16) | (NIB_(B.y) << 20) | (NIB_(B.z) << 24) | (NIB_(B.w) << 28);
    #undef NIB_
  }
  if ((i >> 5) == wj) w |= 1u << (i & 31);
  mw[idx] = w;
}

// weights -> bf16, transposed [N][K]
__global__ void k_conv_w(const float* Wq, const float* Wk, const float* Wv, const float* Wo,
                         const float* W1, const float* W2,
                         u16* wqkvt, u16* wot, u16* w1t, u16* w2t){
  int idx = blockIdx.x*256 + threadIdx.x;
  if (idx < 49152){                      // wqkvt[n<384][k<128]
    int n = idx >> 7, k = idx & 127;
    float v = (n < 128) ? Wq[k*128 + n] : (n < 256 ? Wk[k*128 + (n-128)] : Wv[k*128 + (n-256)]);
    wqkvt[idx] = f2bf(v);
  } else if (idx < 65536){               // wot[n<128][k<128]
    int j = idx - 49152, n = j >> 7, k = j & 127;
    wot[j] = f2bf(Wo[k*128 + n]);
  } else if (idx < 98304){               // w1t[n<256][k<128]
    int j = idx - 65536, n = j >> 7, k = j & 127;
    w1t[j] = f2bf(W1[k*256 + n]);
  } else if (idx < 131072){              // w2t[n<128][k<256]
    int j = idx - 98304, n = j >> 8, k = j & 255;
    w2t[j] = f2bf(W2[k*128 + n]);
  }
}

// QKV GEMM (fused conv_x + knorm): grid 1024 (16 rows each), 4 waves x 96 cols.
__global__ __launch_bounds__(256) void k_qkv(const float* x, const u16* wt,
    const float* bq, const float* bk, const float* bv,
    u16* qw, u16* kw, u16* vt, float* kmax2){
  __shared__ u16 xt[16][136];   // x tile bf16, padded
  __shared__ u16 st[16][392];   // [row][ncol 0..383] epilogue stage, padded
  const int wv = threadIdx.x >> 6, lane = threadIdx.x & 63;
  const int r15 = lane & 15, g = lane >> 4;
  const int m0 = blockIdx.x * 16;
  // load + convert x tile (thread -> row i>>4, cols (i&15)*8 .. +7)
  {
    const int row = threadIdx.x >> 4, c0 = (threadIdx.x & 15) * 8;
    const float* xp = x + (size_t)(m0 + row)*D_ + c0;
    float4 a = *(const float4*)(xp);
    float4 b = *(const float4*)(xp + 4);
    u16x4 o1 = { f2bf(a.x), f2bf(a.y), f2bf(a.z), f2bf(a.w) };
    u16x4 o2 = { f2bf(b.x), f2bf(b.y), f2bf(b.z), f2bf(b.w) };
    *(u16x4*)&xt[row][c0]     = o1;
    *(u16x4*)&xt[row][c0 + 4] = o2;
  }
  __syncthreads();
  f32x4 acc[6] = {};
  #pragma unroll
  for (int kk = 0; kk < D_; kk += 32){
    bf16x8 af = load_frag(&xt[r15][kk + 4*g]);
    #pragma unroll
    for (int nf = 0; nf < 6; nf++){
      const u16* br = wt + (size_t)(wv*96 + nf*16 + r15)*D_ + kk + 4*g;
      acc[nf] = __builtin_amdgcn_mfma_f32_16x16x32_bf16(af, load_frag(br), acc[nf], 0, 0, 0);
    }
  }
  // stage to LDS with bias (+ q scale)
  #pragma unroll
  for (int nf = 0; nf < 6; nf++){
    int ncol = wv*96 + nf*16 + r15;
    float bias = (ncol < 128) ? bq[ncol] : (ncol < 256 ? bk[ncol-128] : bv[ncol-256]);
    float scl  = (ncol < 128) ? 0.17677669529663687f : 1.f;   // 1/sqrt(32) on q
    #pragma unroll
    for (int rr = 0; rr < 4; rr++)
      st[4*g + rr][ncol] = f2bf((acc[nf][rr] + bias) * scl);
  }
  __syncthreads();
  // vectorized emit
  const int b = m0 >> 12, t0m = m0 & (T_-1);
  const int i = threadIdx.x;
  // Q: 256 x 16B. i -> t=i>>4, c=i&15 (h=c>>2, d0=(c&3)*8)
  {
    const int t = i >> 4, c = i & 15, h = c >> 2, d0 = (c & 3)*8;
    uint4 v = *(const uint4*)&st[t][h*32 + d0];
    *(uint4*)(qw + ((size_t)(b*H_ + h)*T_ + (t0m + t))*DH_ + d0) = v;
  }
  // K: 256 x 16B. i -> h=i>>6, seg=(i>>4)&3, trow=i&15.
  {
    const int h = i >> 6, seg = (i >> 4) & 3, trow = i & 15;
    union { u16 e[8]; uint4 u; } v;
    #pragma unroll
    for (int sub = 0; sub < 8; sub++){
      int d = 16*(sub >> 2) + 4*seg + (sub & 3);
      v.e[sub] = st[trow][128 + h*32 + d];
    }
    *(uint4*)(kw + (size_t)(b*H_ + h)*T_*DH_ + (size_t)(t0m >> 4)*512 + seg*128 + trow*8) = v.u;
  }
  // V: 512 x 8B (2 chunks/thread).
  {
    const int bit4 = (t0m >> 4) & 1;
    #pragma unroll
    for (int cc = 0; cc < 2; cc++){
      const int c = i + cc*256;
      const int h = c >> 7, dlhi = (c >> 6) & 1, tq = (c >> 4) & 3, dl15 = c & 15;
      u16x4 v;
      #pragma unroll
      for (int j = 0; j < 4; j++)
        v[j] = st[tq*4 + j][256 + h*32 + dlhi*16 + dl15];
      *(u16x4*)(vt + (size_t)(b*H_ + h)*T_*DH_ + (size_t)(t0m >> 5)*1024
                + dlhi*512 + (size_t)(tq*16 + dl15)*8 + 4*bit4) = v;
    }
  }
  // knorm: per-key ||k||^2 from staged tile; wave-reduce over t (stride 4,8,16,32)
  // then ONLY lanes 0..3 (one per h) issue atomicMax -> 4 atomics/block.
  if (i < 64){
    const int t = i >> 2, h = i & 3;
    float s = 0.f;
    #pragma unroll
    for (int d = 0; d < 32; d++){ float f = bf2f(st[t][128 + h*32 + d]); s += f*f; }
    #pragma unroll
    for (int d = 4; d < 64; d <<= 1) s = fmaxf(s, __shfl_xor(s, d));
    if (i < 4) atomicMax((unsigned*)(kmax2 + (b*H_ + h)), __float_as_uint(s));
  }
}

// Bounded-softmax attention (__expf). Swapped QK^T; shift+mask in C-init;
// l via ones-column MFMA; pack via __float22bfloat162_rn. (exact R10 kernel)
// grid = BH(16) * T/64 = 1024; 4 waves/block, 16 queries/wave. XCD swizzle.
__global__ __launch_bounds__(256, 4) void k_attn16(const u16* qw, const u16* kw, const u16* vt,
    const unsigned* mw, const float* kmax2, u16* ao){
  const int wg = (blockIdx.x & 7)*128 + (blockIdx.x >> 3);   // 8 XCDs x 128 contiguous
  const int wv = threadIdx.x >> 6, lane = threadIdx.x & 63;
  const int r15 = lane & 15, g = lane >> 4;
  const int bh = wg >> 6;
  const int q0 = (wg & 63)*64 + wv*16;
  const u16* qp = qw + (size_t)bh*T_*DH_;
  const u16* kl = kw + (size_t)bh*T_*DH_ + lane*8;   // fragment-major, lane offset folded
  const u16* vl = vt + (size_t)bh*T_*DH_ + lane*8;
  const unsigned* mrow = mw + (size_t)(q0 + r15)*(T_/32);
  const bf16x8 qf = load_frag(qp + (size_t)(q0 + r15)*DH_ + 4*g);
  float n0 = 0.f;
  #pragma unroll
  for (int j = 0; j < 8; j++){ float f = bf2f((u16)qf[j]); n0 += f*f; }
  n0 += __shfl_xor(n0, 16); n0 += __shfl_xor(n0, 32);
  const float bnd = sqrtf(n0 * kmax2[bh]) * 1.0001f + 1e-6f;  // >= max_j |q.k_j|
  union { u16 e[8]; bf16x8 v; } ones;
  #pragma unroll
  for (int j = 0; j < 8; j++) ones.e[j] = 0x3F80;
  f32x4 o0 = {}, o1 = {}, ol = {};
  for (int jb4 = 0; jb4 < T_; jb4 += 128){
    const uint4 wv4 = *(const uint4*)(mrow + (jb4 >> 5));
    #pragma unroll
    for (int ji = 0; ji < 4; ji++){
      const int jb = jb4 + ji*32;
      const unsigned w = ((const unsigned*)&wv4)[ji];
      const unsigned u = w >> (4*g);
      bf16x8 kf0 = *(const bf16x8*)(kl + (size_t)(jb >> 4)*512);
      bf16x8 kf1 = *(const bf16x8*)(kl + (size_t)((jb >> 4) + 1)*512);
      bf16x8 vf0 = *(const bf16x8*)(vl + (size_t)(jb >> 5)*1024);
      bf16x8 vf1 = *(const bf16x8*)(vl + (size_t)(jb >> 5)*1024 + 512);
      f32x4 c0, c1;   // -bnd if masked-in else -1e30 (exp -> 0)
      #pragma unroll
      for (int rr = 0; rr < 4; rr++){
        c0[rr] = ((u >> rr) & 1u)        ? -bnd : -1e30f;
        c1[rr] = ((u >> (16 + rr)) & 1u) ? -bnd : -1e30f;
      }
      f32x4 s0 = __builtin_amdgcn_mfma_f32_16x16x32_bf16(kf0, qf, c0, 0, 0, 0);
      f32x4 s1 = __builtin_amdgcn_mfma_f32_16x16x32_bf16(kf1, qf, c1, 0, 0, 0);
      float p0[4], p1[4];
      #pragma unroll
      for (int rr = 0; rr < 4; rr++){
        p0[rr] = __expf(s0[rr]);
        p1[rr] = __expf(s1[rr]);
      }
      union { bf16x8 v; __hip_bfloat162 h2[4]; } pf;
      pf.h2[0] = __float22bfloat162_rn(make_float2(p0[0], p0[1]));
      pf.h2[1] = __float22bfloat162_rn(make_float2(p0[2], p0[3]));
      pf.h2[2] = __float22bfloat162_rn(make_float2(p1[0], p1[1]));
      pf.h2[3] = __float22bfloat162_rn(make_float2(p1[2], p1[3]));
      o0 = __builtin_amdgcn_mfma_f32_16x16x32_bf16(pf.v, vf0, o0, 0, 0, 0);
      o1 = __builtin_amdgcn_mfma_f32_16x16x32_bf16(pf.v, vf1, o1, 0, 0, 0);
      ol = __builtin_amdgcn_mfma_f32_16x16x32_bf16(pf.v, ones.v, ol, 0, 0, 0);
    }
  }
  const int b = bh >> 2, h = bh & 3;
  #pragma unroll
  for (int rr = 0; rr < 4; rr++){
    float li = ol[rr];                  // l for query 4g+rr, present in every lane
    float inv = li > 0.f ? 1.f/li : 0.f;
    size_t row = (size_t)(b*T_ + q0 + 4*g + rr)*D_;
    ao[row + h*DH_ + r15]      = f2bf(o0[rr]*inv);
    ao[row + h*DH_ + 16 + r15] = f2bf(o1[rr]*inv);
  }
}

// Fused tail: proj+residual+LN1 -> FF1+GELU -> FF2+residual+LN2 -> out.
// grid 1024 (16 rows/block), 4 waves. y/h staged in LDS (padded rows).
__global__ __launch_bounds__(256) void k_tail(const u16* ao, const u16* wot, const float* bo,
    const float* x, const float* g1, const float* be1,
    const u16* w1t, const float* bf1, const u16* w2t, const float* b2,
    const float* g2, const float* be2, float* out){
  __shared__ float ly[16][132];     // y32 (LN1 out, f32) - LN2 residual
  __shared__ u16  lyb[16][136];     // y bf16 (A for FF1)
  __shared__ u16  lhb[16][264];     // gelu(h) bf16 (A for FF2)
  __shared__ float rs[4][16], rq[4][16];
  const int wv = threadIdx.x >> 6, lane = threadIdx.x & 63;
  const int r15 = lane & 15, g = lane >> 4;
  const int m0 = blockIdx.x * 16;

  // ---- stage A: proj GEMM (wave wv -> cols [wv*32, wv*32+32)) ----
  f32x4 accA[2] = {};
  const u16* ar = ao + (size_t)(m0 + r15)*D_ + 4*g;
  #pragma unroll
  for (int kk = 0; kk < D_; kk += 32){
    bf16x8 af = load_frag(ar + kk);
    #pragma unroll
    for (int nf = 0; nf < 2; nf++)
      accA[nf] = __builtin_amdgcn_mfma_f32_16x16x32_bf16(af,
          load_frag(wot + (size_t)((wv*2 + nf)*16 + r15)*D_ + kk + 4*g), accA[nf], 0, 0, 0);
  }
  float tA[2][4];
  #pragma unroll
  for (int rr = 0; rr < 4; rr++){
    float s1 = 0.f, s2 = 0.f;
    #pragma unroll
    for (int nf = 0; nf < 2; nf++){
      int col = (wv*2 + nf)*16 + r15;
      float t = accA[nf][rr] + bo[col] + x[(size_t)(m0 + 4*g + rr)*D_ + col];
      tA[nf][rr] = t; s1 += t; s2 += t*t;
    }
    #pragma unroll
    for (int d = 1; d < 16; d <<= 1){ s1 += __shfl_xor(s1, d); s2 += __shfl_xor(s2, d); }
    if (r15 == 0){ rs[wv][4*g + rr] = s1; rq[wv][4*g + rr] = s2; }
  }
  __syncthreads();
  #pragma unroll
  for (int rr = 0; rr < 4; rr++){
    int row = 4*g + rr;
    float S1 = rs[0][row] + rs[1][row] + rs[2][row] + rs[3][row];
    float S2 = rq[0][row] + rq[1][row] + rq[2][row] + rq[3][row];
    float mu = S1 * (1.f/D_);
    float var = fmaxf(S2 * (1.f/D_) - mu*mu, 0.f);
    float inv = rsqrtf(var + 1e-5f);
    #pragma unroll
    for (int nf = 0; nf < 2; nf++){
      int col = (wv*2 + nf)*16 + r15;
      float o = (tA[nf][rr] - mu)*inv*g1[col] + be1[col];
      ly[row][col] = o;
      lyb[row][col] = f2bf(o);
    }
  }
  __syncthreads();

  // ---- stage B: FF1 + GELU (wave wv -> cols [wv*64, wv*64+64)) ----
  const int n0w = wv*64;
  f32x4 accB[4] = {};
  #pragma unroll
  for (int kk = 0; kk < D_; kk += 32){
    bf16x8 af = load_frag(&lyb[r15][kk + 4*g]);
    #pragma unroll
    for (int nf = 0; nf < 4; nf++)
      accB[nf] = __builtin_amdgcn_mfma_f32_16x16x32_bf16(af,
          load_frag(w1t + (size_t)(n0w + nf*16 + r15)*D_ + kk + 4*g), accB[nf], 0, 0, 0);
  }
  #pragma unroll
  for (int nf = 0; nf < 4; nf++){
    int col = n0w + nf*16 + r15;
    float bias = bf1[col];
    #pragma unroll
    for (int rr = 0; rr < 4; rr++){
      float vv = accB[nf][rr] + bias;
      float z2 = fminf(1.5957691216057308f*vv + 0.07135581778225507f*vv*vv*vv, 80.f);
      float t = __expf(z2);
      lhb[4*g + rr][col] = f2bf(vv * t / (t + 1.f));
    }
  }
  __syncthreads();

  // ---- stage C: FF2 + residual + LN2 (wave wv -> cols [wv*32, wv*32+32)) ----
  f32x4 accC[2] = {};
  #pragma unroll
  for (int kk = 0; kk < FF_; kk += 32){
    bf16x8 af = load_frag(&lhb[r15][kk + 4*g]);
    #pragma unroll
    for (int nf = 0; nf < 2; nf++)
      accC[nf] = __builtin_amdgcn_mfma_f32_16x16x32_bf16(af,
          load_frag(w2t + (size_t)((wv*2 + nf)*16 + r15)*FF_ + kk + 4*g), accC[nf], 0, 0, 0);
  }
  float tC[2][4];
  #pragma unroll
  for (int rr = 0; rr < 4; rr++){
    float s1 = 0.f, s2 = 0.f;
    #pragma unroll
    for (int nf = 0; nf < 2; nf++){
      int col = (wv*2 + nf)*16 + r15;
      float t = accC[nf][rr] + b2[col] + ly[4*g + rr][col];
      tC[nf][rr] = t; s1 += t; s2 += t*t;
    }
    #pragma unroll
    for (int d = 1; d < 16; d <<= 1){ s1 += __shfl_xor(s1, d); s2 += __shfl_xor(s2, d); }
    if (r15 == 0){ rs[wv][4*g + rr] = s1; rq[wv][4*g + rr] = s2; }
  }
  __syncthreads();
  #pragma unroll
  for (int rr = 0; rr < 4; rr++){
    int row = 4*g + rr;
    float S1 = rs[0][row] + rs[1][row] + rs[2][row] + rs[3][row];
    float S2 = rq[0][row] + rq[1][row] + rq[2][row] + rq[3][row];
    float mu = S1 * (1.f/D_);
    float var = fmaxf(S2 * (1.f/D_) - mu*mu, 0.f);
    float inv = rsqrtf(var + 1e-5f);
    #pragma unroll
    for (int nf = 0; nf < 2; nf++){
      int col = (wv*2 + nf)*16 + r15;
      out[(size_t)(m0 + row)*D_ + col] = (tC[nf][rr] - mu)*inv*g2[col] + be2[col];
    }
  }
}

extern "C" void kernel_launch(void* const* d_in, const int* in_sizes, int n_in,
                              void* d_out, int out_size, void* d_ws, size_t ws_size,
                              hipStream_t stream){
  const float* x   = (const float*)d_in[0];
  const void*  msk = d_in[1];
  const float* Wq = (const float*)d_in[2];  const float* bq  = (const float*)d_in[3];
  const float* Wk = (const float*)d_in[4];  const float* bk  = (const float*)d_in[5];
  const float* Wv = (const float*)d_in[6];  const float* bv  = (const float*)d_in[7];
  const float* Wo = (const float*)d_in[8];  const float* bo  = (const float*)d_in[9];
  const float* g1 = (const float*)d_in[10]; const float* be1 = (const float*)d_in[11];
  const float* W1 = (const float*)d_in[12]; const float* bf1 = (const float*)d_in[13];
  const float* W2 = (const float*)d_in[14]; const float* b2  = (const float*)d_in[15];
  const float* g2 = (const float*)d_in[16]; const float* be2 = (const float*)d_in[17];

  char* ws = (char*)d_ws;
  unsigned* flags = (unsigned*)(ws + OFF_FLAG);
  float*    kmax2 = (float*)   (ws + OFF_FLAG + 64);
  unsigned* mw    = (unsigned*)(ws + OFF_MASKW);
  u16* wqkvt = (u16*)(ws + OFF_WQKVT);
  u16* wot   = (u16*)(ws + OFF_WOT);
  u16* w1t   = (u16*)(ws + OFF_W1T);
  u16* w2t   = (u16*)(ws + OFF_W2T);
  u16* qw    = (u16*)(ws + OFF_QW);
  u16* kw    = (u16*)(ws + OFF_KW);
  u16* vt    = (u16*)(ws + OFF_VT);
  u16* ao    = (u16*)(ws + OFF_AO);

  hipMemsetAsync(ws + OFF_FLAG, 1, 8, stream);        // flags = 0x01010101 (true)
  hipMemsetAsync(ws + OFF_FLAG + 64, 0, 64, stream);  // kmax2 = 0
  k_detect<<<64, 256, 0, stream>>>((const unsigned*)msk, flags);
  k_pack  <<<(T_*T_/32)/256, 256, 0, stream>>>(msk, flags, mw);
  k_conv_w<<<131072/256, 256, 0, stream>>>(Wq, Wk, Wv, Wo, W1, W2, wqkvt, wot, w1t, w2t);
  k_qkv   <<<M_/16, 256, 0, stream>>>(x, wqkvt, bq, bk, bv, qw, kw, vt, kmax2);
  k_attn16<<<(B_*H_)*(T_/64), 256, 0, stream>>>(qw, kw, vt, mw, kmax2, ao);
  k_tail  <<<M_/16, 256, 0, stream>>>(ao, wot, bo, x, g1, be1, w1t, bf1, w2t, b2, g2, be2, (float*)d_out);
}

// Round 17
// 169.976 us; speedup vs baseline: 2.1248x; 1.1058x over previous
//
#include <hip/hip_runtime.h>
#include <hip/hip_bf16.h>
#include <math.h>

// GNNLayer: B=4,T=4096,D=128,H=4,DH=32,FF=256
// bf16 MFMA (16x16x32) everywhere, fp32 accum, fp32 LN/residual/bias.
// R17: dispatch consolidation + tail row-tiling:
//      - k_pack + k_conv_w merged into k_prep (independent; branch on blockIdx)
//      - kmax2 zeroed by k_detect block 0 (consumed only by later k_qkv) ->
//        drops one memset. 8 dispatches -> 6.
//      - k_tail: 32 rows/block (grid 512): weight B-frags loaded once per 2
//        row-tiles, half the barrier instances per unit work.
//      attn/qkv byte-identical to R16 (92.5us proven).

#define B_ 4
#define T_ 4096
#define D_ 128
#define H_ 4
#define DH_ 32
#define FF_ 256
#define M_ (B_*T_)

typedef unsigned short u16;
typedef __attribute__((ext_vector_type(8))) short bf16x8;
typedef __attribute__((ext_vector_type(4))) float f32x4;
typedef __attribute__((ext_vector_type(4))) u16 u16x4;

// ---- workspace layout (bytes, 256-aligned) ----
constexpr size_t OFF_FLAG  = 0;     // u32 flags[2] @0, float kmax2[16] @64
constexpr size_t OFF_MASKW = 256;                      // u32[T][T/32] = 2 MB
constexpr size_t OFF_XB    = OFF_MASKW + 2097152;      // (unused)
constexpr size_t OFF_WQKVT = OFF_XB    + 4194304;      // bf16 [384][128]
constexpr size_t OFF_WOT   = OFF_WQKVT + 98304;        // bf16 [128][128]
constexpr size_t OFF_W1T   = OFF_WOT   + 32768;        // bf16 [256][128]
constexpr size_t OFF_W2T   = OFF_W1T   + 65536;        // bf16 [128][256]
constexpr size_t OFF_QW    = OFF_W2T   + 65536;        // bf16 [16][T][32] (q, pre-scaled 1/sqrt(DH))
constexpr size_t OFF_KW    = OFF_QW    + 4194304;      // bf16 [16][T*32] fragment-major
constexpr size_t OFF_VT    = OFF_KW    + 4194304;      // bf16 [16][T*32] fragment-major v^T
constexpr size_t OFF_AO    = OFF_VT    + 4194304;      // bf16 attn out [M][128]

__device__ __forceinline__ u16 f2bf(float f){
  unsigned u = __float_as_uint(f);
  u += 0x7FFFu + ((u >> 16) & 1u);
  return (u16)(u >> 16);
}

__device__ __forceinline__ float bf2f(u16 b){
  return __uint_as_float((unsigned)b << 16);
}

// frag loader (row-major source, global or LDS): p = base + row*stride + k0 + 4*(lane>>4)
__device__ __forceinline__ bf16x8 load_frag(const u16* p){
  union { bf16x8 v; uint2 u[2]; } f;
  f.u[0] = *(const uint2*)(p);
  f.u[1] = *(const uint2*)(p + 16);
  return f.v;
}

// ---- mask dtype detection (64 blocks over first 16384 words) + kmax2 zero ----
__global__ void k_detect(const unsigned* m, unsigned* flags, float* kmax2){
  if (blockIdx.x == 0 && threadIdx.x < 16) kmax2[threadIdx.x] = 0.f;  // consumed by later k_qkv
  const int i = blockIdx.x*256 + threadIdx.x;
  const unsigned w = m[i];
  const int li = (w <= 1u);
  const int lf = (w == 0u || w == 0x3F800000u);
  if (!__all(li)){ if ((threadIdx.x & 63) == 0) atomicAnd(&flags[0], 0u); }
  if (!__all(lf)){ if ((threadIdx.x & 63) == 0) atomicAnd(&flags[1], 0u); }
}

// merged: blocks [0,2048) = mask pack; [2048,2560) = weight convert.
__global__ void k_prep(const void* mask, const unsigned* flags, unsigned* mw,
                       const float* Wq, const float* Wk, const float* Wv, const float* Wo,
                       const float* W1, const float* W2,
                       u16* wqkvt, u16* wot, u16* w1t, u16* w2t){
  if (blockIdx.x < 2048){
    // pack (adj | eye) into bits: mw[i*128 + j/32] bit (j%32)
    int idx = blockIdx.x*256 + threadIdx.x;
    int i = idx >> 7, wj = idx & 127;
    unsigned w = 0;
    if (flags[0] | flags[1]){
      const uint4* p = (const uint4*)((const unsigned*)mask + (size_t)i*T_ + wj*32);
      #pragma unroll
      for (int j = 0; j < 8; j++){
        uint4 v = p[j];
        w |= (unsigned)(v.x != 0u) << (4*j);
        w |= (unsigned)(v.y != 0u) << (4*j + 1);
        w |= (unsigned)(v.z != 0u) << (4*j + 2);
        w |= (unsigned)(v.w != 0u) << (4*j + 3);
      }
    } else {
      const uint4* p = (const uint4*)((const unsigned char*)mask + (size_t)i*T_ + wj*32);
      uint4 A = p[0], B = p[1];
      #define NIB_(d) ((((d) & 0x01010101u) * 0x01020408u) >> 24)
      w  =  NIB_(A.x)        | (NIB_(A.y) << 4)  | (NIB_(A.z) << 8)  | (NIB_(A.w) << 12)
         | (NIB_(B.x) << 16) | (NIB_(B.y) << 20) | (NIB_(B.z) << 24) | (NIB_(B.w) << 28);
      #undef NIB_
    }
    if ((i >> 5) == wj) w |= 1u << (i & 31);
    mw[idx] = w;
  } else {
    // weights -> bf16, transposed [N][K]
    int idx = (blockIdx.x - 2048)*256 + threadIdx.x;
    if (idx < 49152){                      // wqkvt[n<384][k<128]
      int n = idx >> 7, k = idx & 127;
      float v = (n < 128) ? Wq[k*128 + n] : (n < 256 ? Wk[k*128 + (n-128)] : Wv[k*128 + (n-256)]);
      wqkvt[idx] = f2bf(v);
    } else if (idx < 65536){               // wot[n<128][k<128]
      int j = idx - 49152, n = j >> 7, k = j & 127;
      wot[j] = f2bf(Wo[k*128 + n]);
    } else if (idx < 98304){               // w1t[n<256][k<128]
      int j = idx - 65536, n = j >> 7, k = j & 127;
      w1t[j] = f2bf(W1[k*256 + n]);
    } else if (idx < 131072){              // w2t[n<128][k<256]
      int j = idx - 98304, n = j >> 8, k = j & 255;
      w2t[j] = f2bf(W2[k*128 + n]);
    }
  }
}

// QKV GEMM (fused conv_x + knorm): grid 1024 (16 rows each), 4 waves x 96 cols.
__global__ __launch_bounds__(256) void k_qkv(const float* x, const u16* wt,
    const float* bq, const float* bk, const float* bv,
    u16* qw, u16* kw, u16* vt, float* kmax2){
  __shared__ u16 xt[16][136];   // x tile bf16, padded
  __shared__ u16 st[16][392];   // [row][ncol 0..383] epilogue stage, padded
  const int wv = threadIdx.x >> 6, lane = threadIdx.x & 63;
  const int r15 = lane & 15, g = lane >> 4;
  const int m0 = blockIdx.x * 16;
  {
    const int row = threadIdx.x >> 4, c0 = (threadIdx.x & 15) * 8;
    const float* xp = x + (size_t)(m0 + row)*D_ + c0;
    float4 a = *(const float4*)(xp);
    float4 b = *(const float4*)(xp + 4);
    u16x4 o1 = { f2bf(a.x), f2bf(a.y), f2bf(a.z), f2bf(a.w) };
    u16x4 o2 = { f2bf(b.x), f2bf(b.y), f2bf(b.z), f2bf(b.w) };
    *(u16x4*)&xt[row][c0]     = o1;
    *(u16x4*)&xt[row][c0 + 4] = o2;
  }
  __syncthreads();
  f32x4 acc[6] = {};
  #pragma unroll
  for (int kk = 0; kk < D_; kk += 32){
    bf16x8 af = load_frag(&xt[r15][kk + 4*g]);
    #pragma unroll
    for (int nf = 0; nf < 6; nf++){
      const u16* br = wt + (size_t)(wv*96 + nf*16 + r15)*D_ + kk + 4*g;
      acc[nf] = __builtin_amdgcn_mfma_f32_16x16x32_bf16(af, load_frag(br), acc[nf], 0, 0, 0);
    }
  }
  #pragma unroll
  for (int nf = 0; nf < 6; nf++){
    int ncol = wv*96 + nf*16 + r15;
    float bias = (ncol < 128) ? bq[ncol] : (ncol < 256 ? bk[ncol-128] : bv[ncol-256]);
    float scl  = (ncol < 128) ? 0.17677669529663687f : 1.f;   // 1/sqrt(32) on q
    #pragma unroll
    for (int rr = 0; rr < 4; rr++)
      st[4*g + rr][ncol] = f2bf((acc[nf][rr] + bias) * scl);
  }
  __syncthreads();
  const int b = m0 >> 12, t0m = m0 & (T_-1);
  const int i = threadIdx.x;
  {
    const int t = i >> 4, c = i & 15, h = c >> 2, d0 = (c & 3)*8;
    uint4 v = *(const uint4*)&st[t][h*32 + d0];
    *(uint4*)(qw + ((size_t)(b*H_ + h)*T_ + (t0m + t))*DH_ + d0) = v;
  }
  {
    const int h = i >> 6, seg = (i >> 4) & 3, trow = i & 15;
    union { u16 e[8]; uint4 u; } v;
    #pragma unroll
    for (int sub = 0; sub < 8; sub++){
      int d = 16*(sub >> 2) + 4*seg + (sub & 3);
      v.e[sub] = st[trow][128 + h*32 + d];
    }
    *(uint4*)(kw + (size_t)(b*H_ + h)*T_*DH_ + (size_t)(t0m >> 4)*512 + seg*128 + trow*8) = v.u;
  }
  {
    const int bit4 = (t0m >> 4) & 1;
    #pragma unroll
    for (int cc = 0; cc < 2; cc++){
      const int c = i + cc*256;
      const int h = c >> 7, dlhi = (c >> 6) & 1, tq = (c >> 4) & 3, dl15 = c & 15;
      u16x4 v;
      #pragma unroll
      for (int j = 0; j < 4; j++)
        v[j] = st[tq*4 + j][256 + h*32 + dlhi*16 + dl15];
      *(u16x4*)(vt + (size_t)(b*H_ + h)*T_*DH_ + (size_t)(t0m >> 5)*1024
                + dlhi*512 + (size_t)(tq*16 + dl15)*8 + 4*bit4) = v;
    }
  }
  // knorm: wave-reduce over t then 4 atomics/block (lanes 0..3)
  if (i < 64){
    const int t = i >> 2, h = i & 3;
    float s = 0.f;
    #pragma unroll
    for (int d = 0; d < 32; d++){ float f = bf2f(st[t][128 + h*32 + d]); s += f*f; }
    #pragma unroll
    for (int d = 4; d < 64; d <<= 1) s = fmaxf(s, __shfl_xor(s, d));
    if (i < 4) atomicMax((unsigned*)(kmax2 + (b*H_ + h)), __float_as_uint(s));
  }
}

// Bounded-softmax attention (__expf). Swapped QK^T; shift+mask in C-init;
// l via ones-column MFMA; pack via __float22bfloat162_rn. (exact R10 kernel)
__global__ __launch_bounds__(256, 4) void k_attn17(const u16* qw, const u16* kw, const u16* vt,
    const unsigned* mw, const float* kmax2, u16* ao){
  const int wg = (blockIdx.x & 7)*128 + (blockIdx.x >> 3);   // 8 XCDs x 128 contiguous
  const int wv = threadIdx.x >> 6, lane = threadIdx.x & 63;
  const int r15 = lane & 15, g = lane >> 4;
  const int bh = wg >> 6;
  const int q0 = (wg & 63)*64 + wv*16;
  const u16* qp = qw + (size_t)bh*T_*DH_;
  const u16* kl = kw + (size_t)bh*T_*DH_ + lane*8;
  const u16* vl = vt + (size_t)bh*T_*DH_ + lane*8;
  const unsigned* mrow = mw + (size_t)(q0 + r15)*(T_/32);
  const bf16x8 qf = load_frag(qp + (size_t)(q0 + r15)*DH_ + 4*g);
  float n0 = 0.f;
  #pragma unroll
  for (int j = 0; j < 8; j++){ float f = bf2f((u16)qf[j]); n0 += f*f; }
  n0 += __shfl_xor(n0, 16); n0 += __shfl_xor(n0, 32);
  const float bnd = sqrtf(n0 * kmax2[bh]) * 1.0001f + 1e-6f;  // >= max_j |q.k_j|
  union { u16 e[8]; bf16x8 v; } ones;
  #pragma unroll
  for (int j = 0; j < 8; j++) ones.e[j] = 0x3F80;
  f32x4 o0 = {}, o1 = {}, ol = {};
  for (int jb4 = 0; jb4 < T_; jb4 += 128){
    const uint4 wv4 = *(const uint4*)(mrow + (jb4 >> 5));
    #pragma unroll
    for (int ji = 0; ji < 4; ji++){
      const int jb = jb4 + ji*32;
      const unsigned w = ((const unsigned*)&wv4)[ji];
      const unsigned u = w >> (4*g);
      bf16x8 kf0 = *(const bf16x8*)(kl + (size_t)(jb >> 4)*512);
      bf16x8 kf1 = *(const bf16x8*)(kl + (size_t)((jb >> 4) + 1)*512);
      bf16x8 vf0 = *(const bf16x8*)(vl + (size_t)(jb >> 5)*1024);
      bf16x8 vf1 = *(const bf16x8*)(vl + (size_t)(jb >> 5)*1024 + 512);
      f32x4 c0, c1;   // -bnd if masked-in else -1e30 (exp -> 0)
      #pragma unroll
      for (int rr = 0; rr < 4; rr++){
        c0[rr] = ((u >> rr) & 1u)        ? -bnd : -1e30f;
        c1[rr] = ((u >> (16 + rr)) & 1u) ? -bnd : -1e30f;
      }
      f32x4 s0 = __builtin_amdgcn_mfma_f32_16x16x32_bf16(kf0, qf, c0, 0, 0, 0);
      f32x4 s1 = __builtin_amdgcn_mfma_f32_16x16x32_bf16(kf1, qf, c1, 0, 0, 0);
      float p0[4], p1[4];
      #pragma unroll
      for (int rr = 0; rr < 4; rr++){
        p0[rr] = __expf(s0[rr]);
        p1[rr] = __expf(s1[rr]);
      }
      union { bf16x8 v; __hip_bfloat162 h2[4]; } pf;
      pf.h2[0] = __float22bfloat162_rn(make_float2(p0[0], p0[1]));
      pf.h2[1] = __float22bfloat162_rn(make_float2(p0[2], p0[3]));
      pf.h2[2] = __float22bfloat162_rn(make_float2(p1[0], p1[1]));
      pf.h2[3] = __float22bfloat162_rn(make_float2(p1[2], p1[3]));
      o0 = __builtin_amdgcn_mfma_f32_16x16x32_bf16(pf.v, vf0, o0, 0, 0, 0);
      o1 = __builtin_amdgcn_mfma_f32_16x16x32_bf16(pf.v, vf1, o1, 0, 0, 0);
      ol = __builtin_amdgcn_mfma_f32_16x16x32_bf16(pf.v, ones.v, ol, 0, 0, 0);
    }
  }
  const int b = bh >> 2, h = bh & 3;
  #pragma unroll
  for (int rr = 0; rr < 4; rr++){
    float li = ol[rr];
    float inv = li > 0.f ? 1.f/li : 0.f;
    size_t row = (size_t)(b*T_ + q0 + 4*g + rr)*D_;
    ao[row + h*DH_ + r15]      = f2bf(o0[rr]*inv);
    ao[row + h*DH_ + 16 + r15] = f2bf(o1[rr]*inv);
  }
}

// Fused tail, 32 rows/block (grid 512): proj+LN1 -> FF1+GELU -> FF2+LN2.
// Two 16-row MFMA tiles per block; weight B-frags loaded once per pair.
__global__ __launch_bounds__(256) void k_tail(const u16* ao, const u16* wot, const float* bo,
    const float* x, const float* g1, const float* be1,
    const u16* w1t, const float* bf1, const u16* w2t, const float* b2,
    const float* g2, const float* be2, float* out){
  __shared__ float ly[32][132];     // y32 (LN1 out, f32) - LN2 residual
  __shared__ u16  lyb[32][136];     // y bf16 (A for FF1)
  __shared__ u16  lhb[32][264];     // gelu(h) bf16 (A for FF2)
  __shared__ float rs[4][32], rq[4][32];
  const int wv = threadIdx.x >> 6, lane = threadIdx.x & 63;
  const int r15 = lane & 15, g = lane >> 4;
  const int m0 = blockIdx.x * 32;

  // ---- stage A: proj GEMM (wave wv -> cols [wv*32,+32), row-tiles t=0,1) ----
  f32x4 accA[2][2] = {};
  #pragma unroll
  for (int kk = 0; kk < D_; kk += 32){
    bf16x8 af0 = load_frag(ao + (size_t)(m0 + r15)*D_ + kk + 4*g);
    bf16x8 af1 = load_frag(ao + (size_t)(m0 + 16 + r15)*D_ + kk + 4*g);
    #pragma unroll
    for (int nf = 0; nf < 2; nf++){
      bf16x8 bf = load_frag(wot + (size_t)((wv*2 + nf)*16 + r15)*D_ + kk + 4*g);
      accA[0][nf] = __builtin_amdgcn_mfma_f32_16x16x32_bf16(af0, bf, accA[0][nf], 0, 0, 0);
      accA[1][nf] = __builtin_amdgcn_mfma_f32_16x16x32_bf16(af1, bf, accA[1][nf], 0, 0, 0);
    }
  }
  float tA[2][2][4];
  #pragma unroll
  for (int t = 0; t < 2; t++){
    #pragma unroll
    for (int rr = 0; rr < 4; rr++){
      float s1 = 0.f, s2 = 0.f;
      #pragma unroll
      for (int nf = 0; nf < 2; nf++){
        int col = (wv*2 + nf)*16 + r15;
        float v = accA[t][nf][rr] + bo[col] + x[(size_t)(m0 + t*16 + 4*g + rr)*D_ + col];
        tA[t][nf][rr] = v; s1 += v; s2 += v*v;
      }
      #pragma unroll
      for (int d = 1; d < 16; d <<= 1){ s1 += __shfl_xor(s1, d); s2 += __shfl_xor(s2, d); }
      if (r15 == 0){ rs[wv][t*16 + 4*g + rr] = s1; rq[wv][t*16 + 4*g + rr] = s2; }
    }
  }
  __syncthreads();
  #pragma unroll
  for (int t = 0; t < 2; t++){
    #pragma unroll
    for (int rr = 0; rr < 4; rr++){
      int row = t*16 + 4*g + rr;
      float S1 = rs[0][row] + rs[1][row] + rs[2][row] + rs[3][row];
      float S2 = rq[0][row] + rq[1][row] + rq[2][row] + rq[3][row];
      float mu = S1 * (1.f/D_);
      float var = fmaxf(S2 * (1.f/D_) - mu*mu, 0.f);
      float inv = rsqrtf(var + 1e-5f);
      #pragma unroll
      for (int nf = 0; nf < 2; nf++){
        int col = (wv*2 + nf)*16 + r15;
        float o = (tA[t][nf][rr] - mu)*inv*g1[col] + be1[col];
        ly[row][col] = o;
        lyb[row][col] = f2bf(o);
      }
    }
  }
  __syncthreads();

  // ---- stage B: FF1 + GELU (wave wv -> cols [wv*64,+64), row-tiles t=0,1) ----
  const int n0w = wv*64;
  f32x4 accB[2][4] = {};
  #pragma unroll
  for (int kk = 0; kk < D_; kk += 32){
    bf16x8 af0 = load_frag(&lyb[r15][kk + 4*g]);
    bf16x8 af1 = load_frag(&lyb[16 + r15][kk + 4*g]);
    #pragma unroll
    for (int nf = 0; nf < 4; nf++){
      bf16x8 bf = load_frag(w1t + (size_t)(n0w + nf*16 + r15)*D_ + kk + 4*g);
      accB[0][nf] = __builtin_amdgcn_mfma_f32_16x16x32_bf16(af0, bf, accB[0][nf], 0, 0, 0);
      accB[1][nf] = __builtin_amdgcn_mfma_f32_16x16x32_bf16(af1, bf, accB[1][nf], 0, 0, 0);
    }
  }
  #pragma unroll
  for (int t = 0; t < 2; t++){
    #pragma unroll
    for (int nf = 0; nf < 4; nf++){
      int col = n0w + nf*16 + r15;
      float bias = bf1[col];
      #pragma unroll
      for (int rr = 0; rr < 4; rr++){
        float vv = accB[t][nf][rr] + bias;
        float z2 = fminf(1.5957691216057308f*vv + 0.07135581778225507f*vv*vv*vv, 80.f);
        float e = __expf(z2);
        lhb[t*16 + 4*g + rr][col] = f2bf(vv * e / (e + 1.f));
      }
    }
  }
  __syncthreads();

  // ---- stage C: FF2 + residual + LN2 (wave wv -> cols [wv*32,+32), t=0,1) ----
  f32x4 accC[2][2] = {};
  #pragma unroll
  for (int kk = 0; kk < FF_; kk += 32){
    bf16x8 af0 = load_frag(&lhb[r15][kk + 4*g]);
    bf16x8 af1 = load_frag(&lhb[16 + r15][kk + 4*g]);
    #pragma unroll
    for (int nf = 0; nf < 2; nf++){
      bf16x8 bf = load_frag(w2t + (size_t)((wv*2 + nf)*16 + r15)*FF_ + kk + 4*g);
      accC[0][nf] = __builtin_amdgcn_mfma_f32_16x16x32_bf16(af0, bf, accC[0][nf], 0, 0, 0);
      accC[1][nf] = __builtin_amdgcn_mfma_f32_16x16x32_bf16(af1, bf, accC[1][nf], 0, 0, 0);
    }
  }
  float tC[2][2][4];
  #pragma unroll
  for (int t = 0; t < 2; t++){
    #pragma unroll
    for (int rr = 0; rr < 4; rr++){
      float s1 = 0.f, s2 = 0.f;
      #pragma unroll
      for (int nf = 0; nf < 2; nf++){
        int col = (wv*2 + nf)*16 + r15;
        float v = accC[t][nf][rr] + b2[col] + ly[t*16 + 4*g + rr][col];
        tC[t][nf][rr] = v; s1 += v; s2 += v*v;
      }
      #pragma unroll
      for (int d = 1; d < 16; d <<= 1){ s1 += __shfl_xor(s1, d); s2 += __shfl_xor(s2, d); }
      if (r15 == 0){ rs[wv][t*16 + 4*g + rr] = s1; rq[wv][t*16 + 4*g + rr] = s2; }
    }
  }
  __syncthreads();
  #pragma unroll
  for (int t = 0; t < 2; t++){
    #pragma unroll
    for (int rr = 0; rr < 4; rr++){
      int row = t*16 + 4*g + rr;
      float S1 = rs[0][row] + rs[1][row] + rs[2][row] + rs[3][row];
      float S2 = rq[0][row] + rq[1][row] + rq[2][row] + rq[3][row];
      float mu = S1 * (1.f/D_);
      float var = fmaxf(S2 * (1.f/D_) - mu*mu, 0.f);
      float inv = rsqrtf(var + 1e-5f);
      #pragma unroll
      for (int nf = 0; nf < 2; nf++){
        int col = (wv*2 + nf)*16 + r15;
        out[(size_t)(m0 + row)*D_ + col] = (tC[t][nf][rr] - mu)*inv*g2[col] + be2[col];
      }
    }
  }
}

extern "C" void kernel_launch(void* const* d_in, const int* in_sizes, int n_in,
                              void* d_out, int out_size, void* d_ws, size_t ws_size,
                              hipStream_t stream){
  const float* x   = (const float*)d_in[0];
  const void*  msk = d_in[1];
  const float* Wq = (const float*)d_in[2];  const float* bq  = (const float*)d_in[3];
  const float* Wk = (const float*)d_in[4];  const float* bk  = (const float*)d_in[5];
  const float* Wv = (const float*)d_in[6];  const float* bv  = (const float*)d_in[7];
  const float* Wo = (const float*)d_in[8];  const float* bo  = (const float*)d_in[9];
  const float* g1 = (const float*)d_in[10]; const float* be1 = (const float*)d_in[11];
  const float* W1 = (const float*)d_in[12]; const float* bf1 = (const float*)d_in[13];
  const float* W2 = (const float*)d_in[14]; const float* b2  = (const float*)d_in[15];
  const float* g2 = (const float*)d_in[16]; const float* be2 = (const float*)d_in[17];

  char* ws = (char*)d_ws;
  unsigned* flags = (unsigned*)(ws + OFF_FLAG);
  float*    kmax2 = (float*)   (ws + OFF_FLAG + 64);
  unsigned* mw    = (unsigned*)(ws + OFF_MASKW);
  u16* wqkvt = (u16*)(ws + OFF_WQKVT);
  u16* wot   = (u16*)(ws + OFF_WOT);
  u16* w1t   = (u16*)(ws + OFF_W1T);
  u16* w2t   = (u16*)(ws + OFF_W2T);
  u16* qw    = (u16*)(ws + OFF_QW);
  u16* kw    = (u16*)(ws + OFF_KW);
  u16* vt    = (u16*)(ws + OFF_VT);
  u16* ao    = (u16*)(ws + OFF_AO);

  hipMemsetAsync(ws + OFF_FLAG, 1, 8, stream);        // flags = 0x01010101 (true)
  k_detect<<<64, 256, 0, stream>>>((const unsigned*)msk, flags, kmax2);
  k_prep  <<<2560, 256, 0, stream>>>(msk, flags, mw, Wq, Wk, Wv, Wo, W1, W2,
                                     wqkvt, wot, w1t, w2t);
  k_qkv   <<<M_/16, 256, 0, stream>>>(x, wqkvt, bq, bk, bv, qw, kw, vt, kmax2);
  k_attn17<<<(B_*H_)*(T_/64), 256, 0, stream>>>(qw, kw, vt, mw, kmax2, ao);
  k_tail  <<<M_/32, 256, 0, stream>>>(ao, wot, bo, x, g1, be1, w1t, bf1, w2t, b2, g2, be2, (float*)d_out);
}

// Round 18
// 169.326 us; speedup vs baseline: 2.1330x; 1.0038x over previous
//
#include <hip/hip_runtime.h>
#include <hip/hip_bf16.h>
#include <math.h>

// GNNLayer: B=4,T=4096,D=128,H=4,DH=32,FF=256
// bf16 MFMA (16x16x32) everywhere, fp32 accum, fp32 LN/residual/bias.
// R18: attn-only change: software-pipelined K/V loads. VGPR=44 showed the
//      compiler issued fragment loads just-in-time (one tile at a time), so
//      every 32-key tile exposed ~200cy L2 latency (the stubborn 42% stall).
//      Now all 8 K/V frags of a 128-key group load before the group's 4
//      compute tiles. Same math; VGPR ~100-115 (<=128 keeps 4 waves/SIMD).
//      All other kernels byte-identical to R17 (170.0us proven).

#define B_ 4
#define T_ 4096
#define D_ 128
#define H_ 4
#define DH_ 32
#define FF_ 256
#define M_ (B_*T_)

typedef unsigned short u16;
typedef __attribute__((ext_vector_type(8))) short bf16x8;
typedef __attribute__((ext_vector_type(4))) float f32x4;
typedef __attribute__((ext_vector_type(4))) u16 u16x4;

// ---- workspace layout (bytes, 256-aligned) ----
constexpr size_t OFF_FLAG  = 0;     // u32 flags[2] @0, float kmax2[16] @64
constexpr size_t OFF_MASKW = 256;                      // u32[T][T/32] = 2 MB
constexpr size_t OFF_XB    = OFF_MASKW + 2097152;      // (unused)
constexpr size_t OFF_WQKVT = OFF_XB    + 4194304;      // bf16 [384][128]
constexpr size_t OFF_WOT   = OFF_WQKVT + 98304;        // bf16 [128][128]
constexpr size_t OFF_W1T   = OFF_WOT   + 32768;        // bf16 [256][128]
constexpr size_t OFF_W2T   = OFF_W1T   + 65536;        // bf16 [128][256]
constexpr size_t OFF_QW    = OFF_W2T   + 65536;        // bf16 [16][T][32] (q, pre-scaled 1/sqrt(DH))
constexpr size_t OFF_KW    = OFF_QW    + 4194304;      // bf16 [16][T*32] fragment-major
constexpr size_t OFF_VT    = OFF_KW    + 4194304;      // bf16 [16][T*32] fragment-major v^T
constexpr size_t OFF_AO    = OFF_VT    + 4194304;      // bf16 attn out [M][128]

__device__ __forceinline__ u16 f2bf(float f){
  unsigned u = __float_as_uint(f);
  u += 0x7FFFu + ((u >> 16) & 1u);
  return (u16)(u >> 16);
}

__device__ __forceinline__ float bf2f(u16 b){
  return __uint_as_float((unsigned)b << 16);
}

// frag loader (row-major source, global or LDS): p = base + row*stride + k0 + 4*(lane>>4)
__device__ __forceinline__ bf16x8 load_frag(const u16* p){
  union { bf16x8 v; uint2 u[2]; } f;
  f.u[0] = *(const uint2*)(p);
  f.u[1] = *(const uint2*)(p + 16);
  return f.v;
}

// ---- mask dtype detection (64 blocks over first 16384 words) + kmax2 zero ----
__global__ void k_detect(const unsigned* m, unsigned* flags, float* kmax2){
  if (blockIdx.x == 0 && threadIdx.x < 16) kmax2[threadIdx.x] = 0.f;
  const int i = blockIdx.x*256 + threadIdx.x;
  const unsigned w = m[i];
  const int li = (w <= 1u);
  const int lf = (w == 0u || w == 0x3F800000u);
  if (!__all(li)){ if ((threadIdx.x & 63) == 0) atomicAnd(&flags[0], 0u); }
  if (!__all(lf)){ if ((threadIdx.x & 63) == 0) atomicAnd(&flags[1], 0u); }
}

// merged: blocks [0,2048) = mask pack; [2048,2560) = weight convert.
__global__ void k_prep(const void* mask, const unsigned* flags, unsigned* mw,
                       const float* Wq, const float* Wk, const float* Wv, const float* Wo,
                       const float* W1, const float* W2,
                       u16* wqkvt, u16* wot, u16* w1t, u16* w2t){
  if (blockIdx.x < 2048){
    int idx = blockIdx.x*256 + threadIdx.x;
    int i = idx >> 7, wj = idx & 127;
    unsigned w = 0;
    if (flags[0] | flags[1]){
      const uint4* p = (const uint4*)((const unsigned*)mask + (size_t)i*T_ + wj*32);
      #pragma unroll
      for (int j = 0; j < 8; j++){
        uint4 v = p[j];
        w |= (unsigned)(v.x != 0u) << (4*j);
        w |= (unsigned)(v.y != 0u) << (4*j + 1);
        w |= (unsigned)(v.z != 0u) << (4*j + 2);
        w |= (unsigned)(v.w != 0u) << (4*j + 3);
      }
    } else {
      const uint4* p = (const uint4*)((const unsigned char*)mask + (size_t)i*T_ + wj*32);
      uint4 A = p[0], B = p[1];
      #define NIB_(d) ((((d) & 0x01010101u) * 0x01020408u) >> 24)
      w  =  NIB_(A.x)        | (NIB_(A.y) << 4)  | (NIB_(A.z) << 8)  | (NIB_(A.w) << 12)
         | (NIB_(B.x) << 16) | (NIB_(B.y) << 20) | (NIB_(B.z) << 24) | (NIB_(B.w) << 28);
      #undef NIB_
    }
    if ((i >> 5) == wj) w |= 1u << (i & 31);
    mw[idx] = w;
  } else {
    int idx = (blockIdx.x - 2048)*256 + threadIdx.x;
    if (idx < 49152){                      // wqkvt[n<384][k<128]
      int n = idx >> 7, k = idx & 127;
      float v = (n < 128) ? Wq[k*128 + n] : (n < 256 ? Wk[k*128 + (n-128)] : Wv[k*128 + (n-256)]);
      wqkvt[idx] = f2bf(v);
    } else if (idx < 65536){               // wot[n<128][k<128]
      int j = idx - 49152, n = j >> 7, k = j & 127;
      wot[j] = f2bf(Wo[k*128 + n]);
    } else if (idx < 98304){               // w1t[n<256][k<128]
      int j = idx - 65536, n = j >> 7, k = j & 127;
      w1t[j] = f2bf(W1[k*256 + n]);
    } else if (idx < 131072){              // w2t[n<128][k<256]
      int j = idx - 98304, n = j >> 8, k = j & 255;
      w2t[j] = f2bf(W2[k*128 + n]);
    }
  }
}

// QKV GEMM (fused conv_x + knorm): grid 1024 (16 rows each), 4 waves x 96 cols.
__global__ __launch_bounds__(256) void k_qkv(const float* x, const u16* wt,
    const float* bq, const float* bk, const float* bv,
    u16* qw, u16* kw, u16* vt, float* kmax2){
  __shared__ u16 xt[16][136];   // x tile bf16, padded
  __shared__ u16 st[16][392];   // [row][ncol 0..383] epilogue stage, padded
  const int wv = threadIdx.x >> 6, lane = threadIdx.x & 63;
  const int r15 = lane & 15, g = lane >> 4;
  const int m0 = blockIdx.x * 16;
  {
    const int row = threadIdx.x >> 4, c0 = (threadIdx.x & 15) * 8;
    const float* xp = x + (size_t)(m0 + row)*D_ + c0;
    float4 a = *(const float4*)(xp);
    float4 b = *(const float4*)(xp + 4);
    u16x4 o1 = { f2bf(a.x), f2bf(a.y), f2bf(a.z), f2bf(a.w) };
    u16x4 o2 = { f2bf(b.x), f2bf(b.y), f2bf(b.z), f2bf(b.w) };
    *(u16x4*)&xt[row][c0]     = o1;
    *(u16x4*)&xt[row][c0 + 4] = o2;
  }
  __syncthreads();
  f32x4 acc[6] = {};
  #pragma unroll
  for (int kk = 0; kk < D_; kk += 32){
    bf16x8 af = load_frag(&xt[r15][kk + 4*g]);
    #pragma unroll
    for (int nf = 0; nf < 6; nf++){
      const u16* br = wt + (size_t)(wv*96 + nf*16 + r15)*D_ + kk + 4*g;
      acc[nf] = __builtin_amdgcn_mfma_f32_16x16x32_bf16(af, load_frag(br), acc[nf], 0, 0, 0);
    }
  }
  #pragma unroll
  for (int nf = 0; nf < 6; nf++){
    int ncol = wv*96 + nf*16 + r15;
    float bias = (ncol < 128) ? bq[ncol] : (ncol < 256 ? bk[ncol-128] : bv[ncol-256]);
    float scl  = (ncol < 128) ? 0.17677669529663687f : 1.f;   // 1/sqrt(32) on q
    #pragma unroll
    for (int rr = 0; rr < 4; rr++)
      st[4*g + rr][ncol] = f2bf((acc[nf][rr] + bias) * scl);
  }
  __syncthreads();
  const int b = m0 >> 12, t0m = m0 & (T_-1);
  const int i = threadIdx.x;
  {
    const int t = i >> 4, c = i & 15, h = c >> 2, d0 = (c & 3)*8;
    uint4 v = *(const uint4*)&st[t][h*32 + d0];
    *(uint4*)(qw + ((size_t)(b*H_ + h)*T_ + (t0m + t))*DH_ + d0) = v;
  }
  {
    const int h = i >> 6, seg = (i >> 4) & 3, trow = i & 15;
    union { u16 e[8]; uint4 u; } v;
    #pragma unroll
    for (int sub = 0; sub < 8; sub++){
      int d = 16*(sub >> 2) + 4*seg + (sub & 3);
      v.e[sub] = st[trow][128 + h*32 + d];
    }
    *(uint4*)(kw + (size_t)(b*H_ + h)*T_*DH_ + (size_t)(t0m >> 4)*512 + seg*128 + trow*8) = v.u;
  }
  {
    const int bit4 = (t0m >> 4) & 1;
    #pragma unroll
    for (int cc = 0; cc < 2; cc++){
      const int c = i + cc*256;
      const int h = c >> 7, dlhi = (c >> 6) & 1, tq = (c >> 4) & 3, dl15 = c & 15;
      u16x4 v;
      #pragma unroll
      for (int j = 0; j < 4; j++)
        v[j] = st[tq*4 + j][256 + h*32 + dlhi*16 + dl15];
      *(u16x4*)(vt + (size_t)(b*H_ + h)*T_*DH_ + (size_t)(t0m >> 5)*1024
                + dlhi*512 + (size_t)(tq*16 + dl15)*8 + 4*bit4) = v;
    }
  }
  if (i < 64){
    const int t = i >> 2, h = i & 3;
    float s = 0.f;
    #pragma unroll
    for (int d = 0; d < 32; d++){ float f = bf2f(st[t][128 + h*32 + d]); s += f*f; }
    #pragma unroll
    for (int d = 4; d < 64; d <<= 1) s = fmaxf(s, __shfl_xor(s, d));
    if (i < 4) atomicMax((unsigned*)(kmax2 + (b*H_ + h)), __float_as_uint(s));
  }
}

// Bounded-softmax attention (__expf), software-pipelined K/V loads.
// Per 128-key group: load ALL 8 K/V frags, then compute 4 tiles.
// grid = BH(16) * T/64 = 1024; 4 waves/block, 16 queries/wave. XCD swizzle.
__global__ __launch_bounds__(256, 4) void k_attn18(const u16* qw, const u16* kw, const u16* vt,
    const unsigned* mw, const float* kmax2, u16* ao){
  const int wg = (blockIdx.x & 7)*128 + (blockIdx.x >> 3);   // 8 XCDs x 128 contiguous
  const int wv = threadIdx.x >> 6, lane = threadIdx.x & 63;
  const int r15 = lane & 15, g = lane >> 4;
  const int bh = wg >> 6;
  const int q0 = (wg & 63)*64 + wv*16;
  const u16* qp = qw + (size_t)bh*T_*DH_;
  const u16* kl = kw + (size_t)bh*T_*DH_ + lane*8;   // fragment-major, lane offset folded
  const u16* vl = vt + (size_t)bh*T_*DH_ + lane*8;
  const unsigned* mrow = mw + (size_t)(q0 + r15)*(T_/32);
  const bf16x8 qf = load_frag(qp + (size_t)(q0 + r15)*DH_ + 4*g);
  float n0 = 0.f;
  #pragma unroll
  for (int j = 0; j < 8; j++){ float f = bf2f((u16)qf[j]); n0 += f*f; }
  n0 += __shfl_xor(n0, 16); n0 += __shfl_xor(n0, 32);
  const float bnd = sqrtf(n0 * kmax2[bh]) * 1.0001f + 1e-6f;  // >= max_j |q.k_j|
  union { u16 e[8]; bf16x8 v; } ones;
  #pragma unroll
  for (int j = 0; j < 8; j++) ones.e[j] = 0x3F80;
  f32x4 o0 = {}, o1 = {}, ol = {};
  for (int jb4 = 0; jb4 < T_; jb4 += 128){
    const uint4 wv4 = *(const uint4*)(mrow + (jb4 >> 5));
    // ---- issue ALL loads for this 128-key group up front (8 frags/2 per tile x 4) ----
    bf16x8 kf[8], vf[8];
    #pragma unroll
    for (int ji = 0; ji < 4; ji++){
      const int jb = jb4 + ji*32;
      kf[2*ji]     = *(const bf16x8*)(kl + (size_t)(jb >> 4)*512);
      kf[2*ji + 1] = *(const bf16x8*)(kl + (size_t)((jb >> 4) + 1)*512);
      vf[2*ji]     = *(const bf16x8*)(vl + (size_t)(jb >> 5)*1024);
      vf[2*ji + 1] = *(const bf16x8*)(vl + (size_t)(jb >> 5)*1024 + 512);
    }
    // ---- compute the 4 tiles ----
    #pragma unroll
    for (int ji = 0; ji < 4; ji++){
      const unsigned w = ((const unsigned*)&wv4)[ji];
      const unsigned u = w >> (4*g);
      f32x4 c0, c1;   // -bnd if masked-in else -1e30 (exp -> 0)
      #pragma unroll
      for (int rr = 0; rr < 4; rr++){
        c0[rr] = ((u >> rr) & 1u)        ? -bnd : -1e30f;
        c1[rr] = ((u >> (16 + rr)) & 1u) ? -bnd : -1e30f;
      }
      f32x4 s0 = __builtin_amdgcn_mfma_f32_16x16x32_bf16(kf[2*ji],     qf, c0, 0, 0, 0);
      f32x4 s1 = __builtin_amdgcn_mfma_f32_16x16x32_bf16(kf[2*ji + 1], qf, c1, 0, 0, 0);
      float p0[4], p1[4];
      #pragma unroll
      for (int rr = 0; rr < 4; rr++){
        p0[rr] = __expf(s0[rr]);
        p1[rr] = __expf(s1[rr]);
      }
      union { bf16x8 v; __hip_bfloat162 h2[4]; } pf;
      pf.h2[0] = __float22bfloat162_rn(make_float2(p0[0], p0[1]));
      pf.h2[1] = __float22bfloat162_rn(make_float2(p0[2], p0[3]));
      pf.h2[2] = __float22bfloat162_rn(make_float2(p1[0], p1[1]));
      pf.h2[3] = __float22bfloat162_rn(make_float2(p1[2], p1[3]));
      o0 = __builtin_amdgcn_mfma_f32_16x16x32_bf16(pf.v, vf[2*ji],     o0, 0, 0, 0);
      o1 = __builtin_amdgcn_mfma_f32_16x16x32_bf16(pf.v, vf[2*ji + 1], o1, 0, 0, 0);
      ol = __builtin_amdgcn_mfma_f32_16x16x32_bf16(pf.v, ones.v,       ol, 0, 0, 0);
    }
  }
  const int b = bh >> 2, h = bh & 3;
  #pragma unroll
  for (int rr = 0; rr < 4; rr++){
    float li = ol[rr];
    float inv = li > 0.f ? 1.f/li : 0.f;
    size_t row = (size_t)(b*T_ + q0 + 4*g + rr)*D_;
    ao[row + h*DH_ + r15]      = f2bf(o0[rr]*inv);
    ao[row + h*DH_ + 16 + r15] = f2bf(o1[rr]*inv);
  }
}

// Fused tail, 32 rows/block (grid 512): proj+LN1 -> FF1+GELU -> FF2+LN2.
__global__ __launch_bounds__(256) void k_tail(const u16* ao, const u16* wot, const float* bo,
    const float* x, const float* g1, const float* be1,
    const u16* w1t, const float* bf1, const u16* w2t, const float* b2,
    const float* g2, const float* be2, float* out){
  __shared__ float ly[32][132];
  __shared__ u16  lyb[32][136];
  __shared__ u16  lhb[32][264];
  __shared__ float rs[4][32], rq[4][32];
  const int wv = threadIdx.x >> 6, lane = threadIdx.x & 63;
  const int r15 = lane & 15, g = lane >> 4;
  const int m0 = blockIdx.x * 32;

  f32x4 accA[2][2] = {};
  #pragma unroll
  for (int kk = 0; kk < D_; kk += 32){
    bf16x8 af0 = load_frag(ao + (size_t)(m0 + r15)*D_ + kk + 4*g);
    bf16x8 af1 = load_frag(ao + (size_t)(m0 + 16 + r15)*D_ + kk + 4*g);
    #pragma unroll
    for (int nf = 0; nf < 2; nf++){
      bf16x8 bf = load_frag(wot + (size_t)((wv*2 + nf)*16 + r15)*D_ + kk + 4*g);
      accA[0][nf] = __builtin_amdgcn_mfma_f32_16x16x32_bf16(af0, bf, accA[0][nf], 0, 0, 0);
      accA[1][nf] = __builtin_amdgcn_mfma_f32_16x16x32_bf16(af1, bf, accA[1][nf], 0, 0, 0);
    }
  }
  float tA[2][2][4];
  #pragma unroll
  for (int t = 0; t < 2; t++){
    #pragma unroll
    for (int rr = 0; rr < 4; rr++){
      float s1 = 0.f, s2 = 0.f;
      #pragma unroll
      for (int nf = 0; nf < 2; nf++){
        int col = (wv*2 + nf)*16 + r15;
        float v = accA[t][nf][rr] + bo[col] + x[(size_t)(m0 + t*16 + 4*g + rr)*D_ + col];
        tA[t][nf][rr] = v; s1 += v; s2 += v*v;
      }
      #pragma unroll
      for (int d = 1; d < 16; d <<= 1){ s1 += __shfl_xor(s1, d); s2 += __shfl_xor(s2, d); }
      if (r15 == 0){ rs[wv][t*16 + 4*g + rr] = s1; rq[wv][t*16 + 4*g + rr] = s2; }
    }
  }
  __syncthreads();
  #pragma unroll
  for (int t = 0; t < 2; t++){
    #pragma unroll
    for (int rr = 0; rr < 4; rr++){
      int row = t*16 + 4*g + rr;
      float S1 = rs[0][row] + rs[1][row] + rs[2][row] + rs[3][row];
      float S2 = rq[0][row] + rq[1][row] + rq[2][row] + rq[3][row];
      float mu = S1 * (1.f/D_);
      float var = fmaxf(S2 * (1.f/D_) - mu*mu, 0.f);
      float inv = rsqrtf(var + 1e-5f);
      #pragma unroll
      for (int nf = 0; nf < 2; nf++){
        int col = (wv*2 + nf)*16 + r15;
        float o = (tA[t][nf][rr] - mu)*inv*g1[col] + be1[col];
        ly[row][col] = o;
        lyb[row][col] = f2bf(o);
      }
    }
  }
  __syncthreads();

  const int n0w = wv*64;
  f32x4 accB[2][4] = {};
  #pragma unroll
  for (int kk = 0; kk < D_; kk += 32){
    bf16x8 af0 = load_frag(&lyb[r15][kk + 4*g]);
    bf16x8 af1 = load_frag(&lyb[16 + r15][kk + 4*g]);
    #pragma unroll
    for (int nf = 0; nf < 4; nf++){
      bf16x8 bf = load_frag(w1t + (size_t)(n0w + nf*16 + r15)*D_ + kk + 4*g);
      accB[0][nf] = __builtin_amdgcn_mfma_f32_16x16x32_bf16(af0, bf, accB[0][nf], 0, 0, 0);
      accB[1][nf] = __builtin_amdgcn_mfma_f32_16x16x32_bf16(af1, bf, accB[1][nf], 0, 0, 0);
    }
  }
  #pragma unroll
  for (int t = 0; t < 2; t++){
    #pragma unroll
    for (int nf = 0; nf < 4; nf++){
      int col = n0w + nf*16 + r15;
      float bias = bf1[col];
      #pragma unroll
      for (int rr = 0; rr < 4; rr++){
        float vv = accB[t][nf][rr] + bias;
        float z2 = fminf(1.5957691216057308f*vv + 0.07135581778225507f*vv*vv*vv, 80.f);
        float e = __expf(z2);
        lhb[t*16 + 4*g + rr][col] = f2bf(vv * e / (e + 1.f));
      }
    }
  }
  __syncthreads();

  f32x4 accC[2][2] = {};
  #pragma unroll
  for (int kk = 0; kk < FF_; kk += 32){
    bf16x8 af0 = load_frag(&lhb[r15][kk + 4*g]);
    bf16x8 af1 = load_frag(&lhb[16 + r15][kk + 4*g]);
    #pragma unroll
    for (int nf = 0; nf < 2; nf++){
      bf16x8 bf = load_frag(w2t + (size_t)((wv*2 + nf)*16 + r15)*FF_ + kk + 4*g);
      accC[0][nf] = __builtin_amdgcn_mfma_f32_16x16x32_bf16(af0, bf, accC[0][nf], 0, 0, 0);
      accC[1][nf] = __builtin_amdgcn_mfma_f32_16x16x32_bf16(af1, bf, accC[1][nf], 0, 0, 0);
    }
  }
  float tC[2][2][4];
  #pragma unroll
  for (int t = 0; t < 2; t++){
    #pragma unroll
    for (int rr = 0; rr < 4; rr++){
      float s1 = 0.f, s2 = 0.f;
      #pragma unroll
      for (int nf = 0; nf < 2; nf++){
        int col = (wv*2 + nf)*16 + r15;
        float v = accC[t][nf][rr] + b2[col] + ly[t*16 + 4*g + rr][col];
        tC[t][nf][rr] = v; s1 += v; s2 += v*v;
      }
      #pragma unroll
      for (int d = 1; d < 16; d <<= 1){ s1 += __shfl_xor(s1, d); s2 += __shfl_xor(s2, d); }
      if (r15 == 0){ rs[wv][t*16 + 4*g + rr] = s1; rq[wv][t*16 + 4*g + rr] = s2; }
    }
  }
  __syncthreads();
  #pragma unroll
  for (int t = 0; t < 2; t++){
    #pragma unroll
    for (int rr = 0; rr < 4; rr++){
      int row = t*16 + 4*g + rr;
      float S1 = rs[0][row] + rs[1][row] + rs[2][row] + rs[3][row];
      float S2 = rq[0][row] + rq[1][row] + rq[2][row] + rq[3][row];
      float mu = S1 * (1.f/D_);
      float var = fmaxf(S2 * (1.f/D_) - mu*mu, 0.f);
      float inv = rsqrtf(var + 1e-5f);
      #pragma unroll
      for (int nf = 0; nf < 2; nf++){
        int col = (wv*2 + nf)*16 + r15;
        out[(size_t)(m0 + row)*D_ + col] = (tC[t][nf][rr] - mu)*inv*g2[col] + be2[col];
      }
    }
  }
}

extern "C" void kernel_launch(void* const* d_in, const int* in_sizes, int n_in,
                              void* d_out, int out_size, void* d_ws, size_t ws_size,
                              hipStream_t stream){
  const float* x   = (const float*)d_in[0];
  const void*  msk = d_in[1];
  const float* Wq = (const float*)d_in[2];  const float* bq  = (const float*)d_in[3];
  const float* Wk = (const float*)d_in[4];  const float* bk  = (const float*)d_in[5];
  const float* Wv = (const float*)d_in[6];  const float* bv  = (const float*)d_in[7];
  const float* Wo = (const float*)d_in[8];  const float* bo  = (const float*)d_in[9];
  const float* g1 = (const float*)d_in[10]; const float* be1 = (const float*)d_in[11];
  const float* W1 = (const float*)d_in[12]; const float* bf1 = (const float*)d_in[13];
  const float* W2 = (const float*)d_in[14]; const float* b2  = (const float*)d_in[15];
  const float* g2 = (const float*)d_in[16]; const float* be2 = (const float*)d_in[17];

  char* ws = (char*)d_ws;
  unsigned* flags = (unsigned*)(ws + OFF_FLAG);
  float*    kmax2 = (float*)   (ws + OFF_FLAG + 64);
  unsigned* mw    = (unsigned*)(ws + OFF_MASKW);
  u16* wqkvt = (u16*)(ws + OFF_WQKVT);
  u16* wot   = (u16*)(ws + OFF_WOT);
  u16* w1t   = (u16*)(ws + OFF_W1T);
  u16* w2t   = (u16*)(ws + OFF_W2T);
  u16* qw    = (u16*)(ws + OFF_QW);
  u16* kw    = (u16*)(ws + OFF_KW);
  u16* vt    = (u16*)(ws + OFF_VT);
  u16* ao    = (u16*)(ws + OFF_AO);

  hipMemsetAsync(ws + OFF_FLAG, 1, 8, stream);        // flags = 0x01010101 (true)
  k_detect<<<64, 256, 0, stream>>>((const unsigned*)msk, flags, kmax2);
  k_prep  <<<2560, 256, 0, stream>>>(msk, flags, mw, Wq, Wk, Wv, Wo, W1, W2,
                                     wqkvt, wot, w1t, w2t);
  k_qkv   <<<M_/16, 256, 0, stream>>>(x, wqkvt, bq, bk, bv, qw, kw, vt, kmax2);
  k_attn18<<<(B_*H_)*(T_/64), 256, 0, stream>>>(qw, kw, vt, mw, kmax2, ao);
  k_tail  <<<M_/32, 256, 0, stream>>>(ao, wot, bo, x, g1, be1, w1t, bf1, w2t, b2, g2, be2, (float*)d_out);
}